// Round 1
// baseline (42864.325 us; speedup 1.0000x reference)
//
#include <hip/hip_runtime.h>
#include <cstddef>

// ---------------------------------------------------------------------------
// VQ-VAE forward, fp32 baseline.
// Layout conventions: feature maps NCHW fp32. Spatial 64x64 everywhere except
// conv0 input (128x128) and deconv output (128x128). B=8.
// ---------------------------------------------------------------------------

#define F_IN_RELU   1
#define F_OUT_RELU  2
#define F_RESIDUAL  4
#define F_STORE_ZT  8

// ---------------- init: zero loss accumulators ----------------
__global__ void k_init(float* a) { a[0] = 0.f; a[1] = 0.f; }

// ---------------- conv0: 3->256, k4 s2 p1, 128x128 -> 64x64 ----------------
__global__ __launch_bounds__(256) void k_conv0(
    const float* __restrict__ x, const float* __restrict__ w,
    const float* __restrict__ bias, float* __restrict__ out)
{
  int idx = blockIdx.x * 256 + threadIdx.x;
  int xc = idx & 63;
  int yc = (idx >> 6) & 63;
  int co = (idx >> 12) & 255;
  int b  = idx >> 20;
  float acc = bias[co];
  for (int ci = 0; ci < 3; ci++) {
    #pragma unroll
    for (int ky = 0; ky < 4; ky++) {
      int iy = 2 * yc - 1 + ky;
      if (iy < 0 || iy >= 128) continue;
      #pragma unroll
      for (int kx = 0; kx < 4; kx++) {
        int ix = 2 * xc - 1 + kx;
        if (ix < 0 || ix >= 128) continue;
        acc += x[((b * 3 + ci) * 128 + iy) * 128 + ix] *
               w[((co * 3 + ci) * 4 + ky) * 4 + kx];
      }
    }
  }
  out[idx] = acc;
}

// ---------------- BatchNorm (training-mode batch stats) + ReLU, in place ---
// One block per channel; biased variance over B*H*W = 32768 elements.
__global__ __launch_bounds__(256) void k_bn_relu(
    float* __restrict__ t, const float* __restrict__ g,
    const float* __restrict__ beta, int C)
{
  int c = blockIdx.x;
  int tid = threadIdx.x;
  float s = 0.f, s2 = 0.f;
  for (int b = 0; b < 8; b++) {
    float* p = t + ((size_t)(b * C + c)) * 4096;
    for (int i = tid; i < 4096; i += 256) { float v = p[i]; s += v; s2 += v * v; }
  }
  __shared__ float rs[256], rs2[256];
  __shared__ float sc_s, sh_s;
  rs[tid] = s; rs2[tid] = s2;
  __syncthreads();
  for (int off = 128; off > 0; off >>= 1) {
    if (tid < off) { rs[tid] += rs[tid + off]; rs2[tid] += rs2[tid + off]; }
    __syncthreads();
  }
  if (tid == 0) {
    float m = rs[0] * (1.f / 32768.f);
    float var = rs2[0] * (1.f / 32768.f) - m * m;
    float sc = g[c] * rsqrtf(var + 1e-5f);
    sc_s = sc; sh_s = beta[c] - m * sc;
  }
  __syncthreads();
  float scale = sc_s, shift = sh_s;
  for (int b = 0; b < 8; b++) {
    float* p = t + ((size_t)(b * C + c)) * 4096;
    for (int i = tid; i < 4096; i += 256) {
      float v = p[i] * scale + shift;
      p[i] = v > 0.f ? v : 0.f;
    }
  }
}

// ---------------- generic conv, K=3 pad1 or K=1 pad0, 64x64 spatial --------
// Block: 256 thr = 8 x-groups x 32 co-groups; thread tile = 4co x 8x.
// Grid: (Cout/128, 64, 8). Chunks of 8 input channels staged in LDS.
template <int K>
__global__ __launch_bounds__(256) void k_conv(
    const float* __restrict__ in, float* __restrict__ out,
    const float* __restrict__ w, const float* __restrict__ bias,
    int Cin, int flags)
{
  constexpr int K2 = K * K;
  constexpr int IC = (K == 3) ? 198 : 64;   // per-ci staged elements
  __shared__ float s_in[8 * IC];
  __shared__ float s_w[8 * K2 * 132];       // [ci][k][co(128) pad->132]

  int tid = threadIdx.x;
  int tx = tid & 7;        // x-group
  int tc = tid >> 3;       // co-group (0..31)
  int co0 = blockIdx.x * 128;
  int y = blockIdx.y;
  int b = blockIdx.z;
  int Cout = gridDim.x * 128;
  int xb = tx * 8;

  float acc[4][8];
  #pragma unroll
  for (int j = 0; j < 4; j++)
    #pragma unroll
    for (int d = 0; d < 8; d++) acc[j][d] = 0.f;

  for (int ci0 = 0; ci0 < Cin; ci0 += 8) {
    __syncthreads();
    // ---- stage inputs ----
    if (K == 3) {
      for (int i = tid; i < 8 * 198; i += 256) {
        int ci = i / 198, rem = i % 198;
        int r = rem / 66, c = rem % 66;
        int yy = y + r - 1, xx = c - 1;
        float v = 0.f;
        if (yy >= 0 && yy < 64 && xx >= 0 && xx < 64)
          v = in[(((size_t)(b * Cin + ci0 + ci)) * 64 + yy) * 64 + xx];
        if (flags & F_IN_RELU) v = v > 0.f ? v : 0.f;
        s_in[i] = v;
      }
    } else {
      for (int i = tid; i < 8 * 64; i += 256) {
        int ci = i >> 6, c = i & 63;
        float v = in[(((size_t)(b * Cin + ci0 + ci)) * 64 + y) * 64 + c];
        if (flags & F_IN_RELU) v = v > 0.f ? v : 0.f;
        s_in[i] = v;
      }
    }
    // ---- stage weights ----
    if (K == 3) {
      for (int i = tid; i < 128 * 72; i += 256) {
        int co = i / 72, j = i % 72;           // j = ci*9 + k
        s_w[j * 132 + co] = w[((size_t)(co0 + co) * Cin + ci0) * 9 + j];
      }
    } else {
      for (int i = tid; i < 128 * 8; i += 256) {
        int co = i >> 3, ci = i & 7;
        s_w[ci * 132 + co] = w[(size_t)(co0 + co) * Cin + ci0 + ci];
      }
    }
    __syncthreads();
    // ---- compute ----
    for (int ci = 0; ci < 8; ci++) {
      if (K == 3) {
        float iw[3][10];
        #pragma unroll
        for (int r = 0; r < 3; r++)
          #pragma unroll
          for (int c = 0; c < 10; c++)
            iw[r][c] = s_in[(ci * 3 + r) * 66 + xb + c];
        #pragma unroll
        for (int ky = 0; ky < 3; ky++)
          #pragma unroll
          for (int kx = 0; kx < 3; kx++) {
            const float4 wv = *(const float4*)&s_w[(ci * 9 + ky * 3 + kx) * 132 + tc * 4];
            #pragma unroll
            for (int d = 0; d < 8; d++) {
              float iv = iw[ky][d + kx];
              acc[0][d] += wv.x * iv;
              acc[1][d] += wv.y * iv;
              acc[2][d] += wv.z * iv;
              acc[3][d] += wv.w * iv;
            }
          }
      } else {
        const float4 wv = *(const float4*)&s_w[ci * 132 + tc * 4];
        #pragma unroll
        for (int d = 0; d < 8; d++) {
          float iv = s_in[ci * 64 + xb + d];
          acc[0][d] += wv.x * iv;
          acc[1][d] += wv.y * iv;
          acc[2][d] += wv.z * iv;
          acc[3][d] += wv.w * iv;
        }
      }
    }
  }

  // ---- epilogue ----
  float4 bv = *(const float4*)&bias[co0 + tc * 4];
  if (flags & F_STORE_ZT) {
    // transposed store: zt[(b*4096 + y*64 + x)*256 + co] (Cout == 256)
    size_t nbase = (size_t)b * 4096 + (size_t)y * 64 + xb;
    #pragma unroll
    for (int d = 0; d < 8; d++) {
      float4 v = make_float4(acc[0][d] + bv.x, acc[1][d] + bv.y,
                             acc[2][d] + bv.z, acc[3][d] + bv.w);
      *(float4*)&out[(nbase + d) * 256 + co0 + tc * 4] = v;
    }
  } else {
    float bj[4] = {bv.x, bv.y, bv.z, bv.w};
    #pragma unroll
    for (int j = 0; j < 4; j++) {
      int co = co0 + tc * 4 + j;
      float* op = out + (((size_t)b * Cout + co) * 64 + y) * 64 + xb;
      float v[8];
      #pragma unroll
      for (int d = 0; d < 8; d++) v[d] = acc[j][d] + bj[j];
      if (flags & F_RESIDUAL) {
        float4 p0 = *(float4*)op;
        float4 p1 = *(float4*)(op + 4);
        v[0] += p0.x; v[1] += p0.y; v[2] += p0.z; v[3] += p0.w;
        v[4] += p1.x; v[5] += p1.y; v[6] += p1.z; v[7] += p1.w;
      }
      if (flags & F_OUT_RELU) {
        #pragma unroll
        for (int d = 0; d < 8; d++) v[d] = v[d] > 0.f ? v[d] : 0.f;
      }
      *(float4*)op       = make_float4(v[0], v[1], v[2], v[3]);
      *(float4*)(op + 4) = make_float4(v[4], v[5], v[6], v[7]);
    }
  }
}

// ---------------- vector quantizer ----------------
// zt: [N=32768][D=256] (transposed z). cb: [1024][256].
// Block: 8 pixels, 256 threads; thread t scans codes {t, t+256, t+512, t+768}.
// argmin(|c|^2 - 2 z.c)  (|z|^2 is row-constant). Writes zq in NCHW, adds
// sum((q - z)^2) to vq_sum.
__global__ __launch_bounds__(256) void k_vq(
    const float* __restrict__ zt, const float* __restrict__ cb,
    float* __restrict__ zq, float* __restrict__ vq_sum)
{
  __shared__ float zf[8 * 256];
  __shared__ float s_best[256 * 8];
  __shared__ int   s_bidx[256 * 8];
  __shared__ int   s_widx[8];
  __shared__ float red[256];

  int tid = threadIdx.x;
  int n0 = blockIdx.x * 8;

  for (int i = tid; i < 2048; i += 256) zf[i] = zt[(size_t)n0 * 256 + i];
  __syncthreads();

  float best[8];
  int bidx[8];
  #pragma unroll
  for (int p = 0; p < 8; p++) { best[p] = 3.4e38f; bidx[p] = 0; }

  for (int chunk = 0; chunk < 4; chunk++) {
    int c = tid + chunk * 256;
    const float4* crow = (const float4*)(cb + (size_t)c * 256);
    float accp[8];
    #pragma unroll
    for (int p = 0; p < 8; p++) accp[p] = 0.f;
    float ccs = 0.f;
    for (int d4 = 0; d4 < 64; d4++) {
      float4 cv = crow[d4];
      ccs += cv.x * cv.x + cv.y * cv.y + cv.z * cv.z + cv.w * cv.w;
      #pragma unroll
      for (int p = 0; p < 8; p++) {
        float4 zv = *(const float4*)&zf[p * 256 + d4 * 4];
        accp[p] += cv.x * zv.x + cv.y * zv.y + cv.z * zv.z + cv.w * zv.w;
      }
    }
    #pragma unroll
    for (int p = 0; p < 8; p++) {
      float sc = ccs - 2.f * accp[p];
      if (sc < best[p]) { best[p] = sc; bidx[p] = c; }
    }
  }
  #pragma unroll
  for (int p = 0; p < 8; p++) { s_best[tid * 8 + p] = best[p]; s_bidx[tid * 8 + p] = bidx[p]; }
  __syncthreads();
  if (tid < 8) {
    float bvv = 3.4e38f; int bi = 0;
    for (int j = 0; j < 256; j++) {
      float v = s_best[j * 8 + tid];
      if (v < bvv) { bvv = v; bi = s_bidx[j * 8 + tid]; }
    }
    s_widx[tid] = bi;
  }
  __syncthreads();

  float local = 0.f;
  int d = tid;
  for (int p = 0; p < 8; p++) {
    int c = s_widx[p];
    float q = cb[(size_t)c * 256 + d];
    float z = zf[p * 256 + d];
    float df = q - z;
    local += df * df;
    int n = n0 + p;
    int bb = n >> 12, pp = n & 4095;
    zq[((size_t)(bb * 256) + d) * 4096 + pp] = q;
  }
  red[tid] = local;
  __syncthreads();
  for (int off = 128; off > 0; off >>= 1) {
    if (tid < off) red[tid] += red[tid + off];
    __syncthreads();
  }
  if (tid == 0) atomicAdd(vq_sum, red[0]);
}

// ---------------- deconv (ConvTranspose2d 256->3, k4 s2 p1) + recon --------
// out[b,o,y,x] = bias[o] + sum_ci sum_{ky,kx valid} h[b,ci,iy,ix]*w[ci,o,ky,kx]
// where k = y+1-2*iy in [0,4). Also accumulates sum((xr - x)^2).
__global__ __launch_bounds__(256) void k_deconv(
    const float* __restrict__ h, const float* __restrict__ w,
    const float* __restrict__ bias, const float* __restrict__ x,
    float* __restrict__ xr, float* __restrict__ recon_sum)
{
  __shared__ float red[256];
  int idx = blockIdx.x * 256 + threadIdx.x;
  int xc = idx & 127;
  int rem = idx >> 7;
  int yc = rem & 127; rem >>= 7;
  int o = rem % 3;
  int b = rem / 3;

  int vy[2], vky[2], nvy = 0;
  int ky0 = (yc + 1) & 1;
  #pragma unroll
  for (int t = 0; t < 2; t++) {
    int ky = ky0 + 2 * t;
    int iy = (yc + 1 - ky) >> 1;
    if (iy >= 0 && iy < 64) { vky[nvy] = ky; vy[nvy] = iy; nvy++; }
  }
  int vx[2], vkx[2], nvx = 0;
  int kx0 = (xc + 1) & 1;
  #pragma unroll
  for (int t = 0; t < 2; t++) {
    int kx = kx0 + 2 * t;
    int ix = (xc + 1 - kx) >> 1;
    if (ix >= 0 && ix < 64) { vkx[nvx] = kx; vx[nvx] = ix; nvx++; }
  }

  float acc = bias[o];
  for (int ci = 0; ci < 256; ci++) {
    const float* hp = h + ((size_t)(b * 256 + ci)) * 4096;
    const float* wp = w + ((size_t)(ci * 3 + o)) * 16;
    for (int ty = 0; ty < nvy; ty++)
      for (int tx = 0; tx < nvx; tx++)
        acc += hp[vy[ty] * 64 + vx[tx]] * wp[vky[ty] * 4 + vkx[tx]];
  }
  xr[idx] = acc;
  float df = acc - x[idx];
  red[threadIdx.x] = df * df;
  __syncthreads();
  for (int off = 128; off > 0; off >>= 1) {
    if (threadIdx.x < off) red[threadIdx.x] += red[threadIdx.x + off];
    __syncthreads();
  }
  if (threadIdx.x == 0) atomicAdd(recon_sum, red[0]);
}

// ---------------- finalize losses ----------------
__global__ void k_finalize(const float* __restrict__ a, float* __restrict__ out)
{
  float e = a[0] * (1.f / (32768.f * 256.f));   // mean((q-z)^2)
  float recon = a[1] * (1.f / 393216.f);
  out[393216] = recon + 1.25f * e;               // total
  out[393217] = recon;
}

// ---------------------------------------------------------------------------
extern "C" void kernel_launch(void* const* d_in, const int* in_sizes, int n_in,
                              void* d_out, int out_size, void* d_ws, size_t ws_size,
                              hipStream_t stream)
{
  const float* x    = (const float*)d_in[0];
  const float* ec0w = (const float*)d_in[1];
  const float* ec0b = (const float*)d_in[2];
  const float* bn0g = (const float*)d_in[3];
  const float* bn0b = (const float*)d_in[4];
  const float* ec1w = (const float*)d_in[5];
  const float* ec1b = (const float*)d_in[6];
  const float* bn1g = (const float*)d_in[7];
  const float* bn1b = (const float*)d_in[8];
  const float* ec2w = (const float*)d_in[9];
  const float* ec2b = (const float*)d_in[10];
  const float* erw1 = (const float*)d_in[11];
  const float* erb1 = (const float*)d_in[12];
  const float* erw2 = (const float*)d_in[13];
  const float* erb2 = (const float*)d_in[14];
  const float* ec3w = (const float*)d_in[15];
  const float* ec3b = (const float*)d_in[16];
  const float* cb   = (const float*)d_in[17];
  const float* dc0w = (const float*)d_in[18];
  const float* dc0b = (const float*)d_in[19];
  const float* drw1 = (const float*)d_in[20];
  const float* drb1 = (const float*)d_in[21];
  const float* drw2 = (const float*)d_in[22];
  const float* drb2 = (const float*)d_in[23];
  const float* dc1w = (const float*)d_in[24];
  const float* dc1b = (const float*)d_in[25];
  const float* ddw  = (const float*)d_in[26];
  const float* ddb  = (const float*)d_in[27];

  float* ws = (float*)d_ws;
  float* bufA   = ws;                       // 16,777,216 floats (8x512x64x64)
  float* bufB   = ws + 16777216;            // 16,777,216 floats
  float* bufT   = ws + 33554432;            //  4,194,304 floats (8x128x64x64)
  float* bufZt  = ws + 37748736;            //  8,388,608 floats ([32768][256])
  float* accums = ws + 46137344;            //  2 floats: vq_sum, recon_sum

  k_init<<<1, 1, 0, stream>>>(accums);

  // ---- encoder ----
  k_conv0<<<32768, 256, 0, stream>>>(x, ec0w, ec0b, bufA);           // 8x256x64x64
  k_bn_relu<<<256, 256, 0, stream>>>(bufA, bn0g, bn0b, 256);
  k_conv<3><<<dim3(4, 64, 8), 256, 0, stream>>>(bufA, bufB, ec1w, ec1b, 256, 0);
  k_bn_relu<<<512, 256, 0, stream>>>(bufB, bn1g, bn1b, 512);
  k_conv<3><<<dim3(4, 64, 8), 256, 0, stream>>>(bufB, bufA, ec2w, ec2b, 512, 0);
  for (int s = 0; s < 4; s++) {
    for (int i = 0; i < 4; i++) {
      int l = s * 4 + i;
      const float* rw1 = erw1 + (size_t)l * 128 * 512 * 9;
      const float* rb1 = erb1 + (size_t)l * 128;
      const float* rw2 = erw2 + (size_t)l * 512 * 128;
      const float* rb2 = erb2 + (size_t)l * 512;
      k_conv<3><<<dim3(1, 64, 8), 256, 0, stream>>>(bufA, bufT, rw1, rb1, 512,
                                                    F_IN_RELU | F_OUT_RELU);
      k_conv<1><<<dim3(4, 64, 8), 256, 0, stream>>>(bufT, bufA, rw2, rb2, 128,
                                                    F_RESIDUAL | (i == 3 ? F_OUT_RELU : 0));
    }
  }
  k_conv<3><<<dim3(2, 64, 8), 256, 0, stream>>>(bufA, bufZt, ec3w, ec3b, 512, F_STORE_ZT);

  // ---- vector quantizer ----  (zq -> bufB in NCHW)
  k_vq<<<4096, 256, 0, stream>>>(bufZt, cb, bufB, accums + 0);

  // ---- decoder ----
  k_conv<3><<<dim3(4, 64, 8), 256, 0, stream>>>(bufB, bufA, dc0w, dc0b, 256, 0);
  for (int s = 0; s < 4; s++) {
    for (int i = 0; i < 4; i++) {
      int l = s * 4 + i;
      const float* rw1 = drw1 + (size_t)l * 128 * 512 * 9;
      const float* rb1 = drb1 + (size_t)l * 128;
      const float* rw2 = drw2 + (size_t)l * 512 * 128;
      const float* rb2 = drb2 + (size_t)l * 512;
      k_conv<3><<<dim3(1, 64, 8), 256, 0, stream>>>(bufA, bufT, rw1, rb1, 512,
                                                    F_IN_RELU | F_OUT_RELU);
      k_conv<1><<<dim3(4, 64, 8), 256, 0, stream>>>(bufT, bufA, rw2, rb2, 128,
                                                    F_RESIDUAL | (i == 3 ? F_OUT_RELU : 0));
    }
  }
  k_conv<3><<<dim3(2, 64, 8), 256, 0, stream>>>(bufA, bufB, dc1w, dc1b, 512, F_OUT_RELU);

  // ---- deconv + recon loss ----
  k_deconv<<<1536, 256, 0, stream>>>(bufB, ddw, ddb, x, (float*)d_out, accums + 1);
  k_finalize<<<1, 1, 0, stream>>>(accums, (float*)d_out);
}

// Round 2
// 6492.300 us; speedup vs baseline: 6.6023x; 6.6023x over previous
//
#include <hip/hip_runtime.h>
#include <cstddef>

#define F_IN_RELU   1
#define F_OUT_RELU  2
#define F_RESIDUAL  4

typedef __attribute__((ext_vector_type(8))) short short8;
typedef __attribute__((ext_vector_type(4))) short short4v;
typedef __attribute__((ext_vector_type(4))) float floatx4;

__device__ inline float bf2f(short h) {
  union { unsigned int u; float f; } v;
  v.u = ((unsigned int)(unsigned short)h) << 16;
  return v.f;
}
__device__ inline short f2bf(float f) {
  union { float f; unsigned int u; } v; v.f = f;
  unsigned int r = v.u + 0x7fffu + ((v.u >> 16) & 1u);
  return (short)(r >> 16);
}

// ---------------- init: zero bn sums + loss accumulators ----------------
__global__ void k_init(float* p) {
  for (int i = threadIdx.x; i < 3074; i += 256) p[i] = 0.f;
}

// ---------------- weight swizzles ----------------
// fp32 w[Cout][Cin][K][K] -> bf16 wq[co_grp16][kk][ci_chunk32][lane64][8]
__global__ __launch_bounds__(256) void k_wswz(
    const float* __restrict__ w, short* __restrict__ wq,
    int Cin, int K2, int per_layer)
{
  int idx = blockIdx.x * 256 + threadIdx.x;
  if (idx >= per_layer) return;
  int layer = blockIdx.y;
  w  += (size_t)layer * per_layer;
  wq += (size_t)layer * per_layer;
  int nch = Cin >> 5;
  int j = idx & 7;
  int lane = (idx >> 3) & 63;
  int r = idx >> 9;
  int cich = r % nch; int r2 = r / nch;
  int kk = r2 % K2;   int co_grp = r2 / K2;
  int co = co_grp * 16 + (lane & 15);
  int ci = (cich << 5) + ((lane >> 4) << 3) + j;
  wq[idx] = f2bf(w[((size_t)co * Cin + ci) * K2 + kk]);
}

// conv0 weights: w[co][j(48)] -> wt[j][co]  (stays fp32)
__global__ __launch_bounds__(256) void k_wswz0(
    const float* __restrict__ w, float* __restrict__ wt)
{
  int idx = blockIdx.x * 256 + threadIdx.x;
  if (idx >= 12288) return;
  int co = idx & 255, j = idx >> 8;
  wt[j * 256 + co] = w[co * 48 + j];
}

// deconv weights: w[ci][o][kk(16)] -> bf16 wdt[kk][o][ci]
__global__ __launch_bounds__(256) void k_wswz_dd(
    const float* __restrict__ w, short* __restrict__ wdt)
{
  int idx = blockIdx.x * 256 + threadIdx.x;
  if (idx >= 12288) return;
  int ci = idx & 255, t = idx >> 8;
  int o = t % 3, kk = t / 3;
  wdt[idx] = f2bf(w[(ci * 3 + o) * 16 + kk]);
}

// ---------------- conv0: 3->256, k4 s2 p1, NCHW fp32 -> NHWC bf16 ----------
__global__ __launch_bounds__(256) void k_conv0(
    const float* __restrict__ x, const float* __restrict__ wt,
    const float* __restrict__ bias, short* __restrict__ out)
{
  __shared__ float patch[48];
  int bi = blockIdx.x;
  int xc = bi & 63, yc = (bi >> 6) & 63, b = bi >> 12;
  int tid = threadIdx.x;
  if (tid < 48) {
    int ci = tid >> 4, ky = (tid >> 2) & 3, kx = tid & 3;
    int iy = 2 * yc - 1 + ky, ix = 2 * xc - 1 + kx;
    float v = 0.f;
    if ((unsigned)iy < 128u && (unsigned)ix < 128u)
      v = x[((b * 3 + ci) * 128 + iy) * 128 + ix];
    patch[tid] = v;
  }
  __syncthreads();
  float acc = bias[tid];
  #pragma unroll 8
  for (int j = 0; j < 48; ++j) acc += patch[j] * wt[j * 256 + tid];
  out[(size_t)bi * 256 + tid] = f2bf(acc);
}

// ---------------- BN (batch stats) on NHWC bf16 ----------------
__global__ __launch_bounds__(256) void k_bnstat(
    const short* __restrict__ t, float* __restrict__ sums, int C)
{
  int tid = threadIdx.x;
  float s[2] = {0.f, 0.f}, s2[2] = {0.f, 0.f};
  int p0 = blockIdx.x * 128;
  for (int pix = p0; pix < p0 + 128; ++pix) {
    const short* row = t + (size_t)pix * C;
    for (int c = tid, k = 0; c < C; c += 256, ++k) {
      float v = bf2f(row[c]); s[k] += v; s2[k] += v * v;
    }
  }
  for (int c = tid, k = 0; c < C; c += 256, ++k) {
    atomicAdd(&sums[c], s[k]);
    atomicAdd(&sums[C + c], s2[k]);
  }
}

__global__ __launch_bounds__(512) void k_bnfin(
    const float* __restrict__ sums, const float* __restrict__ g,
    const float* __restrict__ beta, float* __restrict__ ss, int C)
{
  int c = threadIdx.x;
  if (c >= C) return;
  float m = sums[c] * (1.f / 32768.f);
  float var = sums[C + c] * (1.f / 32768.f) - m * m;
  float sc = g[c] * rsqrtf(var + 1e-5f);
  ss[c] = sc;
  ss[C + c] = beta[c] - m * sc;
}

__global__ __launch_bounds__(256) void k_bnapply(
    short* __restrict__ t, const float* __restrict__ ss, int C)
{
  int idx = blockIdx.x * 256 + threadIdx.x;
  int c = idx & (C - 1);
  float v = bf2f(t[idx]) * ss[c] + ss[C + c];
  t[idx] = f2bf(v > 0.f ? v : 0.f);
}

// ---------------- MFMA implicit-GEMM conv, NHWC bf16 ----------------
// Block: 128 thr = 2 waves; wave tile 64co x 64px (one y row).
// Grid: (Cout/128, 64, 8).
template <int K>
__global__ __launch_bounds__(128) void k_mconv(
    const short* __restrict__ in, short* __restrict__ out,
    const short* __restrict__ wq, const float* __restrict__ bias,
    int Cin, int Cout, int flags)
{
  constexpr int K2 = K * K;
  constexpr int XS = 40;                 // padded x stride (ushorts)
  constexpr int NX = (K == 3) ? 66 : 64;
  constexpr int NR = (K == 3) ? 3 : 1;
  __shared__ __align__(16) short s_in[NR * NX * XS];

  int tid = threadIdx.x;
  int lane = tid & 63;
  int wave = tid >> 6;
  int m = lane & 15, quad = lane >> 4;
  int y = blockIdx.y, b = blockIdx.z;
  int co_base = blockIdx.x * 128 + wave * 64;
  int nch = Cin >> 5;

  floatx4 acc[4][4];
  #pragma unroll
  for (int f = 0; f < 4; ++f)
    #pragma unroll
    for (int p = 0; p < 4; ++p) acc[f][p] = (floatx4){0.f, 0.f, 0.f, 0.f};

  for (int cich = 0; cich < nch; ++cich) {
    __syncthreads();
    if (K == 3) {
      for (int u = tid; u < 3 * 66 * 4; u += 128) {
        int o = u & 3; int t2 = u >> 2;
        int xp = t2 % 66; int row = t2 / 66;
        int gy = y - 1 + row, gx = xp - 1;
        short8 v = {0, 0, 0, 0, 0, 0, 0, 0};
        if ((unsigned)gy < 64u && (unsigned)gx < 64u)
          v = *(const short8*)&in[((size_t)((b * 64 + gy) * 64 + gx)) * Cin + (cich << 5) + (o << 3)];
        if (flags & F_IN_RELU) {
          #pragma unroll
          for (int i = 0; i < 8; ++i) if (v[i] < 0) v[i] = 0;
        }
        *(short8*)&s_in[(row * 66 + xp) * XS + (o << 3)] = v;
      }
    } else {
      for (int u = tid; u < 256; u += 128) {
        int o = u & 3; int xp = u >> 2;
        short8 v = *(const short8*)&in[((size_t)((b * 64 + y) * 64 + xp)) * Cin + (cich << 5) + (o << 3)];
        if (flags & F_IN_RELU) {
          #pragma unroll
          for (int i = 0; i < 8; ++i) if (v[i] < 0) v[i] = 0;
        }
        *(short8*)&s_in[xp * XS + (o << 3)] = v;
      }
    }
    __syncthreads();

    #pragma unroll
    for (int kk = 0; kk < K2; ++kk) {
      int ky = (K == 3) ? (kk / 3) : 0;
      int kx = (K == 3) ? (kk - ky * 3) : 0;
      short8 af[4];
      #pragma unroll
      for (int f = 0; f < 4; ++f) {
        int cg = blockIdx.x * 8 + wave * 4 + f;
        af[f] = *(const short8*)&wq[(((size_t)(cg * K2 + kk) * nch + cich) * 64 + lane) * 8];
      }
      #pragma unroll
      for (int p = 0; p < 4; ++p) {
        short8 bv = *(const short8*)&s_in[(ky * 66 + p * 16 + m + kx) * XS + (quad << 3)];
        #pragma unroll
        for (int f = 0; f < 4; ++f)
          acc[f][p] = __builtin_amdgcn_mfma_f32_16x16x32_bf16(af[f], bv, acc[f][p], 0, 0, 0);
      }
    }
  }

  int pixbase = (b * 64 + y) * 64;
  #pragma unroll
  for (int f = 0; f < 4; ++f) {
    int co4 = co_base + f * 16 + quad * 4;
    floatx4 bv4 = *(const floatx4*)&bias[co4];
    #pragma unroll
    for (int p = 0; p < 4; ++p) {
      int x = p * 16 + m;
      size_t oidx = (size_t)(pixbase + x) * Cout + co4;
      float v[4];
      #pragma unroll
      for (int r = 0; r < 4; ++r) v[r] = acc[f][p][r] + bv4[r];
      if (flags & F_RESIDUAL) {
        short4v rr = *(const short4v*)&out[oidx];
        #pragma unroll
        for (int r = 0; r < 4; ++r) v[r] += bf2f(rr[r]);
      }
      if (flags & F_OUT_RELU) {
        #pragma unroll
        for (int r = 0; r < 4; ++r) v[r] = v[r] > 0.f ? v[r] : 0.f;
      }
      short4v sv;
      #pragma unroll
      for (int r = 0; r < 4; ++r) sv[r] = f2bf(v[r]);
      *(short4v*)&out[oidx] = sv;
    }
  }
}

// ---------------- vector quantizer (z NHWC bf16 -> zq NHWC bf16) -----------
__global__ __launch_bounds__(256) void k_vq(
    const short* __restrict__ zt, const float* __restrict__ cb,
    short* __restrict__ zq, float* __restrict__ vq_sum)
{
  __shared__ float zf[8 * 256];
  __shared__ float s_best[256 * 8];
  __shared__ int   s_bidx[256 * 8];
  __shared__ int   s_widx[8];
  __shared__ float red[256];

  int tid = threadIdx.x;
  int n0 = blockIdx.x * 8;

  for (int i = tid; i < 2048; i += 256) zf[i] = bf2f(zt[(size_t)n0 * 256 + i]);
  __syncthreads();

  float best[8]; int bidx[8];
  #pragma unroll
  for (int p = 0; p < 8; ++p) { best[p] = 3.4e38f; bidx[p] = 0; }

  for (int chunk = 0; chunk < 4; ++chunk) {
    int c = tid + chunk * 256;
    const float4* crow = (const float4*)(cb + (size_t)c * 256);
    float accp[8];
    #pragma unroll
    for (int p = 0; p < 8; ++p) accp[p] = 0.f;
    float ccs = 0.f;
    for (int d4 = 0; d4 < 64; ++d4) {
      float4 cv = crow[d4];
      ccs += cv.x * cv.x + cv.y * cv.y + cv.z * cv.z + cv.w * cv.w;
      #pragma unroll
      for (int p = 0; p < 8; ++p) {
        const float4 zv = *(const float4*)&zf[p * 256 + d4 * 4];
        accp[p] += cv.x * zv.x + cv.y * zv.y + cv.z * zv.z + cv.w * zv.w;
      }
    }
    #pragma unroll
    for (int p = 0; p < 8; ++p) {
      float sc = ccs - 2.f * accp[p];
      if (sc < best[p]) { best[p] = sc; bidx[p] = c; }
    }
  }
  #pragma unroll
  for (int p = 0; p < 8; ++p) { s_best[tid * 8 + p] = best[p]; s_bidx[tid * 8 + p] = bidx[p]; }
  __syncthreads();
  if (tid < 8) {
    float bvv = 3.4e38f; int bi = 0;
    for (int j = 0; j < 256; ++j) {
      float v = s_best[j * 8 + tid];
      if (v < bvv) { bvv = v; bi = s_bidx[j * 8 + tid]; }
    }
    s_widx[tid] = bi;
  }
  __syncthreads();

  float local = 0.f;
  int d = tid;
  for (int p = 0; p < 8; ++p) {
    int c = s_widx[p];
    float q = cb[(size_t)c * 256 + d];
    float z = zf[p * 256 + d];
    float df = q - z;
    local += df * df;
    zq[(size_t)(n0 + p) * 256 + d] = f2bf(q);
  }
  red[tid] = local;
  __syncthreads();
  for (int off = 128; off > 0; off >>= 1) {
    if (tid < off) red[tid] += red[tid + off];
    __syncthreads();
  }
  if (tid == 0) atomicAdd(vq_sum, red[0]);
}

// ---------------- deconv 256->3, k4 s2 p1 (NHWC bf16 in, NCHW fp32 out) ----
__global__ __launch_bounds__(256) void k_deconv(
    const short* __restrict__ h, const short* __restrict__ wdt,
    const float* __restrict__ bias, const float* __restrict__ x,
    float* __restrict__ xr, float* __restrict__ recon_sum)
{
  __shared__ float red[256];
  int idx = blockIdx.x * 256 + threadIdx.x;
  int xc = idx & 127;
  int yc = (idx >> 7) & 127;
  int b = idx >> 14;

  int vy[2], vky[2], nvy = 0;
  int ky0 = (yc + 1) & 1;
  #pragma unroll
  for (int t = 0; t < 2; ++t) {
    int ky = ky0 + 2 * t;
    int iy = (yc + 1 - ky) >> 1;
    if (iy >= 0 && iy < 64) { vky[nvy] = ky; vy[nvy] = iy; ++nvy; }
  }
  int vx[2], vkx[2], nvx = 0;
  int kx0 = (xc + 1) & 1;
  #pragma unroll
  for (int t = 0; t < 2; ++t) {
    int kx = kx0 + 2 * t;
    int ix = (xc + 1 - kx) >> 1;
    if (ix >= 0 && ix < 64) { vkx[nvx] = kx; vx[nvx] = ix; ++nvx; }
  }

  float acc[3] = {bias[0], bias[1], bias[2]};
  for (int ty = 0; ty < nvy; ++ty)
    for (int tx = 0; tx < nvx; ++tx) {
      int kk = vky[ty] * 4 + vkx[tx];
      const short* hp = h + ((size_t)((b * 64 + vy[ty]) * 64 + vx[tx])) * 256;
      const short* wp = wdt + kk * 768;
      for (int c = 0; c < 256; c += 8) {
        short8 hv = *(const short8*)&hp[c];
        short8 w0 = *(const short8*)&wp[c];
        short8 w1 = *(const short8*)&wp[256 + c];
        short8 w2 = *(const short8*)&wp[512 + c];
        #pragma unroll
        for (int i = 0; i < 8; ++i) {
          float hf = bf2f(hv[i]);
          acc[0] += hf * bf2f(w0[i]);
          acc[1] += hf * bf2f(w1[i]);
          acc[2] += hf * bf2f(w2[i]);
        }
      }
    }

  float local = 0.f;
  #pragma unroll
  for (int o = 0; o < 3; ++o) {
    size_t oi = ((size_t)(b * 3 + o) * 128 + yc) * 128 + xc;
    xr[oi] = acc[o];
    float df = acc[o] - x[oi];
    local += df * df;
  }
  red[threadIdx.x] = local;
  __syncthreads();
  for (int off = 128; off > 0; off >>= 1) {
    if (threadIdx.x < off) red[threadIdx.x] += red[threadIdx.x + off];
    __syncthreads();
  }
  if (threadIdx.x == 0) atomicAdd(recon_sum, red[0]);
}

// ---------------- finalize ----------------
__global__ void k_finalize(const float* __restrict__ a, float* __restrict__ out)
{
  float e = a[0] * (1.f / (32768.f * 256.f));
  float recon = a[1] * (1.f / 393216.f);
  out[393216] = recon + 1.25f * e;
  out[393217] = recon;
}

// ---------------------------------------------------------------------------
extern "C" void kernel_launch(void* const* d_in, const int* in_sizes, int n_in,
                              void* d_out, int out_size, void* d_ws, size_t ws_size,
                              hipStream_t stream)
{
  const float* x    = (const float*)d_in[0];
  const float* ec0w = (const float*)d_in[1];
  const float* ec0b = (const float*)d_in[2];
  const float* bn0g = (const float*)d_in[3];
  const float* bn0b = (const float*)d_in[4];
  const float* ec1w = (const float*)d_in[5];
  const float* ec1b = (const float*)d_in[6];
  const float* bn1g = (const float*)d_in[7];
  const float* bn1b = (const float*)d_in[8];
  const float* ec2w = (const float*)d_in[9];
  const float* ec2b = (const float*)d_in[10];
  const float* erw1 = (const float*)d_in[11];
  const float* erb1 = (const float*)d_in[12];
  const float* erw2 = (const float*)d_in[13];
  const float* erb2 = (const float*)d_in[14];
  const float* ec3w = (const float*)d_in[15];
  const float* ec3b = (const float*)d_in[16];
  const float* cb   = (const float*)d_in[17];
  const float* dc0w = (const float*)d_in[18];
  const float* dc0b = (const float*)d_in[19];
  const float* drw1 = (const float*)d_in[20];
  const float* drb1 = (const float*)d_in[21];
  const float* drw2 = (const float*)d_in[22];
  const float* drb2 = (const float*)d_in[23];
  const float* dc1w = (const float*)d_in[24];
  const float* dc1b = (const float*)d_in[25];
  const float* ddw  = (const float*)d_in[26];
  const float* ddb  = (const float*)d_in[27];

  short* wsu = (short*)d_ws;
  short* wq_ec1 = wsu;                       // 1,179,648
  short* wq_ec2 = wsu + 1179648;             // 2,359,296
  short* wq_ec3 = wsu + 3538944;             // 1,179,648
  short* wq_dc0 = wsu + 4718592;             // 1,179,648
  short* wq_dc1 = wsu + 5898240;             // 1,179,648
  short* wq_er1 = wsu + 7077888;             // 16 x 589,824
  short* wq_er2 = wsu + 16515072;            // 16 x 65,536
  short* wq_dr1 = wsu + 17563648;            // 16 x 589,824
  short* wq_dr2 = wsu + 27000832;            // 16 x 65,536
  short* wq_dd  = wsu + 28049408;            // 12,288
  short* bufA   = wsu + 28061696;            // 16,777,216 (NHWC, C<=512)
  short* bufB   = wsu + 44838912;            // 16,777,216
  short* bufZ   = wsu + 61616128;            //  8,388,608 (C=256)
  short* bufT   = wsu + 70004736;            //  4,194,304 (C=128)
  float* stats  = (float*)(wsu + 74199040);  // 3072 floats + 2 accums
  float* bn0_sums = stats;         float* bn0_ss = stats + 512;
  float* bn1_sums = stats + 1024;  float* bn1_ss = stats + 2048;
  float* accums   = stats + 3072;
  float* wt0      = stats + 3080;            // 12,288 fp32 conv0 weights

  k_init<<<1, 256, 0, stream>>>(stats);

  // ---- weight swizzles ----
  k_wswz0<<<48, 256, 0, stream>>>(ec0w, wt0);
  k_wswz_dd<<<48, 256, 0, stream>>>(ddw, wq_dd);
  k_wswz<<<4608, 256, 0, stream>>>(ec1w, wq_ec1, 256, 9, 1179648);
  k_wswz<<<9216, 256, 0, stream>>>(ec2w, wq_ec2, 512, 9, 2359296);
  k_wswz<<<4608, 256, 0, stream>>>(ec3w, wq_ec3, 512, 9, 1179648);
  k_wswz<<<4608, 256, 0, stream>>>(dc0w, wq_dc0, 256, 9, 1179648);
  k_wswz<<<4608, 256, 0, stream>>>(dc1w, wq_dc1, 512, 9, 1179648);
  k_wswz<<<dim3(2304, 16), 256, 0, stream>>>(erw1, wq_er1, 512, 9, 589824);
  k_wswz<<<dim3(256, 16), 256, 0, stream>>>(erw2, wq_er2, 128, 1, 65536);
  k_wswz<<<dim3(2304, 16), 256, 0, stream>>>(drw1, wq_dr1, 512, 9, 589824);
  k_wswz<<<dim3(256, 16), 256, 0, stream>>>(drw2, wq_dr2, 128, 1, 65536);

  // ---- encoder ----
  k_conv0<<<32768, 256, 0, stream>>>(x, wt0, ec0b, bufA);
  k_bnstat<<<256, 256, 0, stream>>>(bufA, bn0_sums, 256);
  k_bnfin<<<1, 512, 0, stream>>>(bn0_sums, bn0g, bn0b, bn0_ss, 256);
  k_bnapply<<<32768, 256, 0, stream>>>(bufA, bn0_ss, 256);

  k_mconv<3><<<dim3(4, 64, 8), 128, 0, stream>>>(bufA, bufB, wq_ec1, ec1b, 256, 512, 0);
  k_bnstat<<<256, 256, 0, stream>>>(bufB, bn1_sums, 512);
  k_bnfin<<<1, 512, 0, stream>>>(bn1_sums, bn1g, bn1b, bn1_ss, 512);
  k_bnapply<<<65536, 256, 0, stream>>>(bufB, bn1_ss, 512);

  k_mconv<3><<<dim3(4, 64, 8), 128, 0, stream>>>(bufB, bufA, wq_ec2, ec2b, 512, 512, 0);

  for (int l = 0; l < 16; ++l) {
    k_mconv<3><<<dim3(1, 64, 8), 128, 0, stream>>>(bufA, bufT, wq_er1 + (size_t)l * 589824,
                                                   erb1 + l * 128, 512, 128,
                                                   F_IN_RELU | F_OUT_RELU);
    k_mconv<1><<<dim3(4, 64, 8), 128, 0, stream>>>(bufT, bufA, wq_er2 + (size_t)l * 65536,
                                                   erb2 + l * 512, 128, 512,
                                                   F_RESIDUAL | (((l & 3) == 3) ? F_OUT_RELU : 0));
  }
  k_mconv<3><<<dim3(2, 64, 8), 128, 0, stream>>>(bufA, bufZ, wq_ec3, ec3b, 512, 256, 0);

  // ---- VQ ----
  k_vq<<<4096, 256, 0, stream>>>(bufZ, cb, bufB, accums + 0);

  // ---- decoder ----
  k_mconv<3><<<dim3(4, 64, 8), 128, 0, stream>>>(bufB, bufA, wq_dc0, dc0b, 256, 512, 0);
  for (int l = 0; l < 16; ++l) {
    k_mconv<3><<<dim3(1, 64, 8), 128, 0, stream>>>(bufA, bufT, wq_dr1 + (size_t)l * 589824,
                                                   drb1 + l * 128, 512, 128,
                                                   F_IN_RELU | F_OUT_RELU);
    k_mconv<1><<<dim3(4, 64, 8), 128, 0, stream>>>(bufT, bufA, wq_dr2 + (size_t)l * 65536,
                                                   drb2 + l * 512, 128, 512,
                                                   F_RESIDUAL | (((l & 3) == 3) ? F_OUT_RELU : 0));
  }
  k_mconv<3><<<dim3(2, 64, 8), 128, 0, stream>>>(bufA, bufB, wq_dc1, dc1b, 512, 256, F_OUT_RELU);

  // ---- deconv + losses ----
  k_deconv<<<512, 256, 0, stream>>>(bufB, wq_dd, ddb, x, (float*)d_out, accums + 1);
  k_finalize<<<1, 1, 0, stream>>>(accums, (float*)d_out);
}

// Round 3
// 5138.153 us; speedup vs baseline: 8.3424x; 1.2635x over previous
//
#include <hip/hip_runtime.h>
#include <cstddef>

#define F_IN_RELU    1
#define F_OUT_RELU   2
#define F_RESIDUAL   4
#define F_IN_F32PAIR 8
#define F_SPLIT      16

typedef __attribute__((ext_vector_type(8))) short short8;
typedef __attribute__((ext_vector_type(4))) short short4v;
typedef __attribute__((ext_vector_type(4))) float floatx4;

__device__ inline float bf2f(short h) {
  union { unsigned int u; float f; } v;
  v.u = ((unsigned int)(unsigned short)h) << 16;
  return v.f;
}
__device__ inline short f2bf(float f) {
  union { float f; unsigned int u; } v; v.f = f;
  unsigned int r = v.u + 0x7fffu + ((v.u >> 16) & 1u);
  return (short)(r >> 16);
}

// ---------------- init: zero bn sums + loss accumulators ----------------
__global__ void k_init(float* p) {
  for (int i = threadIdx.x; i < 3074; i += 256) p[i] = 0.f;
}

// ---------------- weight swizzles ----------------
// fp32 w[Cout][Cin][K][K] -> bf16 wq[co_grp16][kk][ci_chunk32][lane64][8]
__global__ __launch_bounds__(256) void k_wswz(
    const float* __restrict__ w, short* __restrict__ wq,
    int Cin, int K2, int per_layer)
{
  int idx = blockIdx.x * 256 + threadIdx.x;
  if (idx >= per_layer) return;
  int layer = blockIdx.y;
  w  += (size_t)layer * per_layer;
  wq += (size_t)layer * per_layer;
  int nch = Cin >> 5;
  int j = idx & 7;
  int lane = (idx >> 3) & 63;
  int r = idx >> 9;
  int cich = r % nch; int r2 = r / nch;
  int kk = r2 % K2;   int co_grp = r2 / K2;
  int co = co_grp * 16 + (lane & 15);
  int ci = (cich << 5) + ((lane >> 4) << 3) + j;
  wq[idx] = f2bf(w[((size_t)co * Cin + ci) * K2 + kk]);
}

// conv0 weights: w[co][j(48)] -> wt[j][co]  (stays fp32)
__global__ __launch_bounds__(256) void k_wswz0(
    const float* __restrict__ w, float* __restrict__ wt)
{
  int idx = blockIdx.x * 256 + threadIdx.x;
  if (idx >= 12288) return;
  int co = idx & 255, j = idx >> 8;
  wt[j * 256 + co] = w[co * 48 + j];
}

// deconv weights: w[ci][o][kk(16)] -> bf16 wdt[kk][o][ci]
__global__ __launch_bounds__(256) void k_wswz_dd(
    const float* __restrict__ w, short* __restrict__ wdt)
{
  int idx = blockIdx.x * 256 + threadIdx.x;
  if (idx >= 12288) return;
  int ci = idx & 255, t = idx >> 8;
  int o = t % 3, kk = t / 3;
  wdt[idx] = f2bf(w[(ci * 3 + o) * 16 + kk]);
}

// codebook norms |c|^2
__global__ __launch_bounds__(256) void k_ccn(
    const float* __restrict__ cb, float* __restrict__ cc)
{
  int code = blockIdx.x * 256 + threadIdx.x;
  const float4* r = (const float4*)(cb + (size_t)code * 256);
  float s = 0.f;
  for (int i = 0; i < 64; ++i) {
    float4 v = r[i];
    s += v.x * v.x + v.y * v.y + v.z * v.z + v.w * v.w;
  }
  cc[code] = s;
}

// ---------------- conv0: 3->256, k4 s2 p1, NCHW fp32 -> NHWC bf16 ----------
__global__ __launch_bounds__(256) void k_conv0(
    const float* __restrict__ x, const float* __restrict__ wt,
    const float* __restrict__ bias, short* __restrict__ out)
{
  __shared__ float patch[48];
  int bi = blockIdx.x;
  int xc = bi & 63, yc = (bi >> 6) & 63, b = bi >> 12;
  int tid = threadIdx.x;
  if (tid < 48) {
    int ci = tid >> 4, ky = (tid >> 2) & 3, kx = tid & 3;
    int iy = 2 * yc - 1 + ky, ix = 2 * xc - 1 + kx;
    float v = 0.f;
    if ((unsigned)iy < 128u && (unsigned)ix < 128u)
      v = x[((b * 3 + ci) * 128 + iy) * 128 + ix];
    patch[tid] = v;
  }
  __syncthreads();
  float acc = bias[tid];
  #pragma unroll 8
  for (int j = 0; j < 48; ++j) acc += patch[j] * wt[j * 256 + tid];
  out[(size_t)bi * 256 + tid] = f2bf(acc);
}

// ---------------- BN (batch stats) on NHWC bf16 ----------------
// grid 128; block = 4 lane-groups of 64; lane covers 8 consecutive channels.
__global__ __launch_bounds__(256) void k_bnstat(
    const short* __restrict__ t, float* __restrict__ sums, int C)
{
  int tid = threadIdx.x, lane = tid & 63, sub = tid >> 6;
  int c0 = lane * 8;
  bool active = c0 < C;
  float s[8], s2[8];
  #pragma unroll
  for (int i = 0; i < 8; ++i) { s[i] = 0.f; s2[i] = 0.f; }
  int base_pix = blockIdx.x * 256;
  if (active) {
    for (int p = sub; p < 256; p += 4) {
      short8 v = *(const short8*)&t[(size_t)(base_pix + p) * C + c0];
      #pragma unroll
      for (int i = 0; i < 8; ++i) { float f = bf2f(v[i]); s[i] += f; s2[i] += f * f; }
    }
    #pragma unroll
    for (int i = 0; i < 8; ++i) {
      atomicAdd(&sums[c0 + i], s[i]);
      atomicAdd(&sums[C + c0 + i], s2[i]);
    }
  }
}

__global__ __launch_bounds__(512) void k_bnfin(
    const float* __restrict__ sums, const float* __restrict__ g,
    const float* __restrict__ beta, float* __restrict__ ss, int C)
{
  int c = threadIdx.x;
  if (c >= C) return;
  float m = sums[c] * (1.f / 32768.f);
  float var = sums[C + c] * (1.f / 32768.f) - m * m;
  float sc = g[c] * rsqrtf(var + 1e-5f);
  ss[c] = sc;
  ss[C + c] = beta[c] - m * sc;
}

// thread handles 8 consecutive shorts
__global__ __launch_bounds__(256) void k_bnapply(
    short* __restrict__ t, const float* __restrict__ ss, int C)
{
  size_t base = ((size_t)blockIdx.x * 256 + threadIdx.x) * 8;
  int c = (int)(base & (size_t)(C - 1));
  short8 v = *(const short8*)&t[base];
  floatx4 sc0 = *(const floatx4*)&ss[c];
  floatx4 sc1 = *(const floatx4*)&ss[c + 4];
  floatx4 sh0 = *(const floatx4*)&ss[C + c];
  floatx4 sh1 = *(const floatx4*)&ss[C + c + 4];
  short8 o;
  #pragma unroll
  for (int i = 0; i < 4; ++i) {
    float a = bf2f(v[i]) * sc0[i] + sh0[i];
    float b = bf2f(v[4 + i]) * sc1[i] + sh1[i];
    o[i] = f2bf(a > 0.f ? a : 0.f);
    o[4 + i] = f2bf(b > 0.f ? b : 0.f);
  }
  *(short8*)&t[base] = o;
}

// ---------------- MFMA implicit-GEMM conv, NHWC bf16 ----------------
// Block: 128 thr = 2 waves; wave tile 64co x 64px (one y row).
template <int K>
__global__ __launch_bounds__(128) void k_mconv(
    const short* __restrict__ in, short* __restrict__ out,
    float* __restrict__ outf,
    const float* __restrict__ sA, const float* __restrict__ sB,
    const float* __restrict__ bias_t,
    const short* __restrict__ wq, const float* __restrict__ bias,
    int Cin, int c0, int c1, int Cout, int flags)
{
  constexpr int K2 = K * K;
  constexpr int XS = 40;                 // padded x stride (ushorts)
  constexpr int NX = (K == 3) ? 66 : 64;
  constexpr int NR = (K == 3) ? 3 : 1;
  __shared__ __align__(16) short s_in[NR * NX * XS];
  __shared__ float btl[128];

  int tid = threadIdx.x;
  int lane = tid & 63;
  int wave = tid >> 6;
  int m = lane & 15, quad = lane >> 4;
  int y = blockIdx.y, b = blockIdx.z;
  int coblk = (flags & F_SPLIT) ? 0 : blockIdx.x;
  int co_base = coblk * 128 + wave * 64;
  int nch = Cin >> 5;
  int pixbase = (b * 64 + y) * 64;

  if (flags & F_IN_F32PAIR) btl[tid] = bias_t[tid];

  int cc0 = c0, cc1 = c1;
  if (flags & F_SPLIT) {
    int half = nch >> 1;
    cc0 = blockIdx.x * half; cc1 = cc0 + half;
    outf += (size_t)blockIdx.x * 4194304;
  }

  floatx4 acc[4][4];
  #pragma unroll
  for (int f = 0; f < 4; ++f)
    #pragma unroll
    for (int p = 0; p < 4; ++p) acc[f][p] = (floatx4){0.f, 0.f, 0.f, 0.f};

  for (int cich = cc0; cich < cc1; ++cich) {
    __syncthreads();
    if (K == 3) {
      for (int u = tid; u < 3 * 66 * 4; u += 128) {
        int o = u & 3; int t2 = u >> 2;
        int xp = t2 % 66; int row = t2 / 66;
        int gy = y - 1 + row, gx = xp - 1;
        short8 v = {0, 0, 0, 0, 0, 0, 0, 0};
        if ((unsigned)gy < 64u && (unsigned)gx < 64u)
          v = *(const short8*)&in[((size_t)((b * 64 + gy) * 64 + gx)) * Cin + (cich << 5) + (o << 3)];
        if (flags & F_IN_RELU) {
          #pragma unroll
          for (int i = 0; i < 8; ++i) if (v[i] < 0) v[i] = 0;
        }
        *(short8*)&s_in[(row * 66 + xp) * XS + (o << 3)] = v;
      }
    } else {
      if (flags & F_IN_F32PAIR) {
        for (int u = tid; u < 256; u += 128) {
          int o = u & 3; int xp = u >> 2;
          int ch = (cich << 5) + (o << 3);
          size_t base = (size_t)(pixbase + xp) * 128 + ch;
          floatx4 a0 = *(const floatx4*)&sA[base];
          floatx4 a0b = *(const floatx4*)&sA[base + 4];
          floatx4 a1 = *(const floatx4*)&sB[base];
          floatx4 a1b = *(const floatx4*)&sB[base + 4];
          short8 v;
          #pragma unroll
          for (int i = 0; i < 4; ++i) {
            float va = a0[i] + a1[i] + btl[ch + i];
            float vb = a0b[i] + a1b[i] + btl[ch + 4 + i];
            v[i] = f2bf(va > 0.f ? va : 0.f);
            v[4 + i] = f2bf(vb > 0.f ? vb : 0.f);
          }
          *(short8*)&s_in[xp * XS + (o << 3)] = v;
        }
      } else {
        for (int u = tid; u < 256; u += 128) {
          int o = u & 3; int xp = u >> 2;
          short8 v = *(const short8*)&in[((size_t)(pixbase + xp)) * Cin + (cich << 5) + (o << 3)];
          if (flags & F_IN_RELU) {
            #pragma unroll
            for (int i = 0; i < 8; ++i) if (v[i] < 0) v[i] = 0;
          }
          *(short8*)&s_in[xp * XS + (o << 3)] = v;
        }
      }
    }
    __syncthreads();

    #pragma unroll
    for (int kk = 0; kk < K2; ++kk) {
      int ky = (K == 3) ? (kk / 3) : 0;
      int kx = (K == 3) ? (kk - ky * 3) : 0;
      short8 af[4];
      #pragma unroll
      for (int f = 0; f < 4; ++f) {
        int cg = coblk * 8 + wave * 4 + f;
        af[f] = *(const short8*)&wq[(((size_t)(cg * K2 + kk) * nch + cich) * 64 + lane) * 8];
      }
      #pragma unroll
      for (int p = 0; p < 4; ++p) {
        short8 bv = *(const short8*)&s_in[(ky * 66 + p * 16 + m + kx) * XS + (quad << 3)];
        #pragma unroll
        for (int f = 0; f < 4; ++f)
          acc[f][p] = __builtin_amdgcn_mfma_f32_16x16x32_bf16(af[f], bv, acc[f][p], 0, 0, 0);
      }
    }
  }

  if (flags & F_SPLIT) {
    #pragma unroll
    for (int f = 0; f < 4; ++f) {
      int co_l = wave * 64 + f * 16 + quad * 4;
      #pragma unroll
      for (int p = 0; p < 4; ++p) {
        int x = p * 16 + m;
        *(floatx4*)&outf[(size_t)(pixbase + x) * 128 + co_l] = acc[f][p];
      }
    }
    return;
  }

  #pragma unroll
  for (int f = 0; f < 4; ++f) {
    int co4 = co_base + f * 16 + quad * 4;
    floatx4 bv4 = *(const floatx4*)&bias[co4];
    #pragma unroll
    for (int p = 0; p < 4; ++p) {
      int x = p * 16 + m;
      size_t oidx = (size_t)(pixbase + x) * Cout + co4;
      float v[4];
      #pragma unroll
      for (int r = 0; r < 4; ++r) v[r] = acc[f][p][r] + bv4[r];
      if (flags & F_RESIDUAL) {
        short4v rr = *(const short4v*)&out[oidx];
        #pragma unroll
        for (int r = 0; r < 4; ++r) v[r] += bf2f(rr[r]);
      }
      if (flags & F_OUT_RELU) {
        #pragma unroll
        for (int r = 0; r < 4; ++r) v[r] = v[r] > 0.f ? v[r] : 0.f;
      }
      short4v sv;
      #pragma unroll
      for (int r = 0; r < 4; ++r) sv[r] = f2bf(v[r]);
      *(short4v*)&out[oidx] = sv;
    }
  }
}

// ---------------- MFMA vector quantizer ----------------
// Block: 64 px, 128 thr (2 waves, each 2 px-frags). Scores = |c|^2 - 2 c.z
// via bf16 MFMA; per-lane running argmin; cross-quad shfl reduce.
__global__ __launch_bounds__(128) void k_vqm(
    const short* __restrict__ z, const short* __restrict__ cbq,
    const float* __restrict__ cb, const float* __restrict__ cc,
    short* __restrict__ zq, float* __restrict__ vq_sum)
{
  __shared__ __align__(16) short zl[64 * 264];
  __shared__ float ccl[1024];
  __shared__ int widx[64];
  __shared__ float red[128];

  int tid = threadIdx.x;
  int lane = tid & 63, wave = tid >> 6;
  int m = lane & 15, quad = lane >> 4;
  size_t px0 = (size_t)blockIdx.x * 64;

  for (int u = tid; u < 64 * 32; u += 128) {
    int px = u >> 5, o = u & 31;
    *(short8*)&zl[px * 264 + o * 8] = *(const short8*)&z[(px0 + px) * 256 + o * 8];
  }
  for (int u = tid; u < 1024; u += 128) ccl[u] = cc[u];
  __syncthreads();

  // preload B-frags (z) for this wave's 2 px-frags x 8 k-chunks
  short8 bf[2][8];
  #pragma unroll
  for (int f = 0; f < 2; ++f) {
    int px = wave * 32 + f * 16 + m;
    #pragma unroll
    for (int kc = 0; kc < 8; ++kc)
      bf[f][kc] = *(const short8*)&zl[px * 264 + kc * 32 + quad * 8];
  }

  float best[2] = {3.4e38f, 3.4e38f};
  int bid[2] = {0, 0};

  for (int cg = 0; cg < 64; ++cg) {
    floatx4 acc0 = (floatx4){0.f, 0.f, 0.f, 0.f};
    floatx4 acc1 = (floatx4){0.f, 0.f, 0.f, 0.f};
    #pragma unroll
    for (int kc = 0; kc < 8; ++kc) {
      short8 af = *(const short8*)&cbq[((size_t)(cg * 8 + kc) * 64 + lane) * 8];
      acc0 = __builtin_amdgcn_mfma_f32_16x16x32_bf16(af, bf[0][kc], acc0, 0, 0, 0);
      acc1 = __builtin_amdgcn_mfma_f32_16x16x32_bf16(af, bf[1][kc], acc1, 0, 0, 0);
    }
    floatx4 c4 = *(const floatx4*)&ccl[cg * 16 + quad * 4];
    #pragma unroll
    for (int r = 0; r < 4; ++r) {
      int code = cg * 16 + quad * 4 + r;
      float s0 = c4[r] - 2.f * acc0[r];
      float s1 = c4[r] - 2.f * acc1[r];
      if (s0 < best[0]) { best[0] = s0; bid[0] = code; }
      if (s1 < best[1]) { best[1] = s1; bid[1] = code; }
    }
  }

  #pragma unroll
  for (int f = 0; f < 2; ++f) {
    float s = best[f]; int i = bid[f];
    #pragma unroll
    for (int off = 16; off <= 32; off <<= 1) {
      float s2 = __shfl_xor(s, off);
      int i2 = __shfl_xor(i, off);
      if (s2 < s || (s2 == s && i2 < i)) { s = s2; i = i2; }
    }
    if (quad == 0) widx[wave * 32 + f * 16 + m] = i;
  }
  __syncthreads();

  float local = 0.f;
  for (int px = 0; px < 64; ++px) {
    int code = widx[px];
    #pragma unroll
    for (int k = 0; k < 2; ++k) {
      int d = tid + k * 128;
      float q = cb[(size_t)code * 256 + d];
      float zv = bf2f(zl[px * 264 + d]);
      float df = q - zv;
      local += df * df;
      zq[(px0 + px) * 256 + d] = f2bf(q);
    }
  }
  red[tid] = local;
  __syncthreads();
  for (int off = 64; off > 0; off >>= 1) {
    if (tid < off) red[tid] += red[tid + off];
    __syncthreads();
  }
  if (tid == 0) atomicAdd(vq_sum, red[0]);
}

// ---------------- deconv 256->3, k4 s2 p1 (NHWC bf16 in, NCHW fp32 out) ----
__global__ __launch_bounds__(256) void k_deconv(
    const short* __restrict__ h, const short* __restrict__ wdt,
    const float* __restrict__ bias, const float* __restrict__ x,
    float* __restrict__ xr, float* __restrict__ recon_sum)
{
  __shared__ float red[256];
  int idx = blockIdx.x * 256 + threadIdx.x;
  int xc = idx & 127;
  int yc = (idx >> 7) & 127;
  int b = idx >> 14;

  int vy[2], vky[2], nvy = 0;
  int ky0 = (yc + 1) & 1;
  #pragma unroll
  for (int t = 0; t < 2; ++t) {
    int ky = ky0 + 2 * t;
    int iy = (yc + 1 - ky) >> 1;
    if (iy >= 0 && iy < 64) { vky[nvy] = ky; vy[nvy] = iy; ++nvy; }
  }
  int vx[2], vkx[2], nvx = 0;
  int kx0 = (xc + 1) & 1;
  #pragma unroll
  for (int t = 0; t < 2; ++t) {
    int kx = kx0 + 2 * t;
    int ix = (xc + 1 - kx) >> 1;
    if (ix >= 0 && ix < 64) { vkx[nvx] = kx; vx[nvx] = ix; ++nvx; }
  }

  float acc[3] = {bias[0], bias[1], bias[2]};
  for (int ty = 0; ty < nvy; ++ty)
    for (int tx = 0; tx < nvx; ++tx) {
      int kk = vky[ty] * 4 + vkx[tx];
      const short* hp = h + ((size_t)((b * 64 + vy[ty]) * 64 + vx[tx])) * 256;
      const short* wp = wdt + kk * 768;
      for (int c = 0; c < 256; c += 8) {
        short8 hv = *(const short8*)&hp[c];
        short8 w0 = *(const short8*)&wp[c];
        short8 w1 = *(const short8*)&wp[256 + c];
        short8 w2 = *(const short8*)&wp[512 + c];
        #pragma unroll
        for (int i = 0; i < 8; ++i) {
          float hf = bf2f(hv[i]);
          acc[0] += hf * bf2f(w0[i]);
          acc[1] += hf * bf2f(w1[i]);
          acc[2] += hf * bf2f(w2[i]);
        }
      }
    }

  float local = 0.f;
  #pragma unroll
  for (int o = 0; o < 3; ++o) {
    size_t oi = ((size_t)(b * 3 + o) * 128 + yc) * 128 + xc;
    xr[oi] = acc[o];
    float df = acc[o] - x[oi];
    local += df * df;
  }
  red[threadIdx.x] = local;
  __syncthreads();
  for (int off = 128; off > 0; off >>= 1) {
    if (threadIdx.x < off) red[threadIdx.x] += red[threadIdx.x + off];
    __syncthreads();
  }
  if (threadIdx.x == 0) atomicAdd(recon_sum, red[0]);
}

// ---------------- finalize ----------------
__global__ void k_finalize(const float* __restrict__ a, float* __restrict__ out)
{
  float e = a[0] * (1.f / (32768.f * 256.f));
  float recon = a[1] * (1.f / 393216.f);
  out[393216] = recon + 1.25f * e;
  out[393217] = recon;
}

// ---------------------------------------------------------------------------
extern "C" void kernel_launch(void* const* d_in, const int* in_sizes, int n_in,
                              void* d_out, int out_size, void* d_ws, size_t ws_size,
                              hipStream_t stream)
{
  const float* x    = (const float*)d_in[0];
  const float* ec0w = (const float*)d_in[1];
  const float* ec0b = (const float*)d_in[2];
  const float* bn0g = (const float*)d_in[3];
  const float* bn0b = (const float*)d_in[4];
  const float* ec1w = (const float*)d_in[5];
  const float* ec1b = (const float*)d_in[6];
  const float* bn1g = (const float*)d_in[7];
  const float* bn1b = (const float*)d_in[8];
  const float* ec2w = (const float*)d_in[9];
  const float* ec2b = (const float*)d_in[10];
  const float* erw1 = (const float*)d_in[11];
  const float* erb1 = (const float*)d_in[12];
  const float* erw2 = (const float*)d_in[13];
  const float* erb2 = (const float*)d_in[14];
  const float* ec3w = (const float*)d_in[15];
  const float* ec3b = (const float*)d_in[16];
  const float* cb   = (const float*)d_in[17];
  const float* dc0w = (const float*)d_in[18];
  const float* dc0b = (const float*)d_in[19];
  const float* drw1 = (const float*)d_in[20];
  const float* drb1 = (const float*)d_in[21];
  const float* drw2 = (const float*)d_in[22];
  const float* drb2 = (const float*)d_in[23];
  const float* dc1w = (const float*)d_in[24];
  const float* dc1b = (const float*)d_in[25];
  const float* ddw  = (const float*)d_in[26];
  const float* ddb  = (const float*)d_in[27];

  short* wsu = (short*)d_ws;
  short* wq_ec1 = wsu;                       // 1,179,648
  short* wq_ec2 = wsu + 1179648;             // 2,359,296
  short* wq_ec3 = wsu + 3538944;             // 1,179,648
  short* wq_dc0 = wsu + 4718592;             // 1,179,648
  short* wq_dc1 = wsu + 5898240;             // 1,179,648
  short* wq_er1 = wsu + 7077888;             // 16 x 589,824
  short* wq_er2 = wsu + 16515072;            // 16 x 65,536
  short* wq_dr1 = wsu + 17563648;            // 16 x 589,824
  short* wq_dr2 = wsu + 27000832;            // 16 x 65,536
  short* wq_dd  = wsu + 28049408;            // 12,288
  short* cbq    = wsu + 28061696;            // 262,144
  short* bufA   = wsu + 28323840;            // 16,777,216 (NHWC, C<=512)
  short* bufB   = wsu + 45101056;            // 16,777,216
  short* bufZ   = wsu + 61878272;            //  8,388,608 (C=256)
  float* fbase  = (float*)d_ws;
  float* scr    = fbase + 35133440;          // 2 x 4,194,304 fp32 split scratch
  float* stats  = scr + 8388608;             // 3074
  float* bn0_sums = stats;         float* bn0_ss = stats + 512;
  float* bn1_sums = stats + 1024;  float* bn1_ss = stats + 2048;
  float* accums   = stats + 3072;
  float* wt0      = stats + 3080;            // 12,288 fp32 conv0 weights
  float* ccn      = wt0 + 12288;             // 1024 codebook norms

  k_init<<<1, 256, 0, stream>>>(stats);

  // ---- weight swizzles ----
  k_wswz0<<<48, 256, 0, stream>>>(ec0w, wt0);
  k_wswz_dd<<<48, 256, 0, stream>>>(ddw, wq_dd);
  k_ccn<<<4, 256, 0, stream>>>(cb, ccn);
  k_wswz<<<1024, 256, 0, stream>>>(cb, cbq, 256, 1, 262144);
  k_wswz<<<4608, 256, 0, stream>>>(ec1w, wq_ec1, 256, 9, 1179648);
  k_wswz<<<9216, 256, 0, stream>>>(ec2w, wq_ec2, 512, 9, 2359296);
  k_wswz<<<4608, 256, 0, stream>>>(ec3w, wq_ec3, 512, 9, 1179648);
  k_wswz<<<4608, 256, 0, stream>>>(dc0w, wq_dc0, 256, 9, 1179648);
  k_wswz<<<4608, 256, 0, stream>>>(dc1w, wq_dc1, 512, 9, 1179648);
  k_wswz<<<dim3(2304, 16), 256, 0, stream>>>(erw1, wq_er1, 512, 9, 589824);
  k_wswz<<<dim3(256, 16), 256, 0, stream>>>(erw2, wq_er2, 128, 1, 65536);
  k_wswz<<<dim3(2304, 16), 256, 0, stream>>>(drw1, wq_dr1, 512, 9, 589824);
  k_wswz<<<dim3(256, 16), 256, 0, stream>>>(drw2, wq_dr2, 128, 1, 65536);

  // ---- encoder ----
  k_conv0<<<32768, 256, 0, stream>>>(x, wt0, ec0b, bufA);
  k_bnstat<<<128, 256, 0, stream>>>(bufA, bn0_sums, 256);
  k_bnfin<<<1, 512, 0, stream>>>(bn0_sums, bn0g, bn0b, bn0_ss, 256);
  k_bnapply<<<4096, 256, 0, stream>>>(bufA, bn0_ss, 256);

  k_mconv<3><<<dim3(4, 64, 8), 128, 0, stream>>>(bufA, bufB, nullptr, nullptr, nullptr, nullptr,
                                                 wq_ec1, ec1b, 256, 0, 8, 512, 0);
  k_bnstat<<<128, 256, 0, stream>>>(bufB, bn1_sums, 512);
  k_bnfin<<<1, 512, 0, stream>>>(bn1_sums, bn1g, bn1b, bn1_ss, 512);
  k_bnapply<<<8192, 256, 0, stream>>>(bufB, bn1_ss, 512);

  k_mconv<3><<<dim3(4, 64, 8), 128, 0, stream>>>(bufB, bufA, nullptr, nullptr, nullptr, nullptr,
                                                 wq_ec2, ec2b, 512, 0, 16, 512, 0);

  for (int l = 0; l < 16; ++l) {
    k_mconv<3><<<dim3(2, 64, 8), 128, 0, stream>>>(bufA, nullptr, scr, nullptr, nullptr, nullptr,
                                                   wq_er1 + (size_t)l * 589824, nullptr,
                                                   512, 0, 0, 128, F_IN_RELU | F_SPLIT);
    k_mconv<1><<<dim3(4, 64, 8), 128, 0, stream>>>(nullptr, bufA, nullptr, scr, scr + 4194304,
                                                   erb1 + l * 128,
                                                   wq_er2 + (size_t)l * 65536, erb2 + l * 512,
                                                   128, 0, 4, 512,
                                                   F_IN_F32PAIR | F_RESIDUAL | (((l & 3) == 3) ? F_OUT_RELU : 0));
  }
  k_mconv<3><<<dim3(2, 64, 8), 128, 0, stream>>>(bufA, bufZ, nullptr, nullptr, nullptr, nullptr,
                                                 wq_ec3, ec3b, 512, 0, 16, 256, 0);

  // ---- VQ ----
  k_vqm<<<512, 128, 0, stream>>>(bufZ, cbq, cb, ccn, bufB, accums + 0);

  // ---- decoder ----
  k_mconv<3><<<dim3(4, 64, 8), 128, 0, stream>>>(bufB, bufA, nullptr, nullptr, nullptr, nullptr,
                                                 wq_dc0, dc0b, 256, 0, 8, 512, 0);
  for (int l = 0; l < 16; ++l) {
    k_mconv<3><<<dim3(2, 64, 8), 128, 0, stream>>>(bufA, nullptr, scr, nullptr, nullptr, nullptr,
                                                   wq_dr1 + (size_t)l * 589824, nullptr,
                                                   512, 0, 0, 128, F_IN_RELU | F_SPLIT);
    k_mconv<1><<<dim3(4, 64, 8), 128, 0, stream>>>(nullptr, bufA, nullptr, scr, scr + 4194304,
                                                   drb1 + l * 128,
                                                   wq_dr2 + (size_t)l * 65536, drb2 + l * 512,
                                                   128, 0, 4, 512,
                                                   F_IN_F32PAIR | F_RESIDUAL | (((l & 3) == 3) ? F_OUT_RELU : 0));
  }
  k_mconv<3><<<dim3(2, 64, 8), 128, 0, stream>>>(bufA, bufB, nullptr, nullptr, nullptr, nullptr,
                                                 wq_dc1, dc1b, 512, 0, 16, 256, F_OUT_RELU);

  // ---- deconv + losses ----
  k_deconv<<<512, 256, 0, stream>>>(bufB, wq_dd, ddb, x, (float*)d_out, accums + 1);
  k_finalize<<<1, 1, 0, stream>>>(accums, (float*)d_out);
}

// Round 4
// 4417.899 us; speedup vs baseline: 9.7024x; 1.1630x over previous
//
#include <hip/hip_runtime.h>
#include <cstddef>

#define F_IN_RELU    1
#define F_OUT_RELU   2
#define F_RESIDUAL   4
#define F_IN_BFPAIR  8
#define F_SPLIT      16

typedef __attribute__((ext_vector_type(8))) short short8;
typedef __attribute__((ext_vector_type(4))) short short4v;
typedef __attribute__((ext_vector_type(4))) float floatx4;

__device__ inline float bf2f(short h) {
  union { unsigned int u; float f; } v;
  v.u = ((unsigned int)(unsigned short)h) << 16;
  return v.f;
}
__device__ inline short f2bf(float f) {
  union { float f; unsigned int u; } v; v.f = f;
  unsigned int r = v.u + 0x7fffu + ((v.u >> 16) & 1u);
  return (short)(r >> 16);
}

// ---------------- init: zero bn sums + loss accumulators ----------------
__global__ void k_init(float* p) {
  for (int i = threadIdx.x; i < 3074; i += 256) p[i] = 0.f;
}

// ---------------- weight swizzles ----------------
// fp32 w[Cout][Cin][K][K] -> bf16 wq[co_grp16][kk][ci_chunk32][lane64][8]
__global__ __launch_bounds__(256) void k_wswz(
    const float* __restrict__ w, short* __restrict__ wq,
    int Cin, int K2, int per_layer)
{
  int idx = blockIdx.x * 256 + threadIdx.x;
  if (idx >= per_layer) return;
  int layer = blockIdx.y;
  w  += (size_t)layer * per_layer;
  wq += (size_t)layer * per_layer;
  int nch = Cin >> 5;
  int j = idx & 7;
  int lane = (idx >> 3) & 63;
  int r = idx >> 9;
  int cich = r % nch; int r2 = r / nch;
  int kk = r2 % K2;   int co_grp = r2 / K2;
  int co = co_grp * 16 + (lane & 15);
  int ci = (cich << 5) + ((lane >> 4) << 3) + j;
  wq[idx] = f2bf(w[((size_t)co * Cin + ci) * K2 + kk]);
}

// conv0 weights -> A-frag layout with K padded 48->64
__global__ __launch_bounds__(256) void k_wswz0m(
    const float* __restrict__ w, short* __restrict__ wq)
{
  int idx = blockIdx.x * 256 + threadIdx.x;
  if (idx >= 16384) return;
  int co = idx >> 6, k = idx & 63;
  float val = (k < 48) ? w[co * 48 + k] : 0.f;
  int cich = k >> 5;
  int lane = (((k >> 3) & 3) << 4) | (co & 15);
  int j = k & 7;
  int cg = co >> 4;
  wq[((size_t)(cg * 2 + cich) * 64 + lane) * 8 + j] = f2bf(val);
}

// im2col for conv0: out[px][64] bf16, k = ci*16+ky*4+kx, padded with zeros
__global__ __launch_bounds__(256) void k_im2col(
    const float* __restrict__ x, short* __restrict__ out)
{
  int idx = blockIdx.x * 256 + threadIdx.x;
  int k = idx & 63;
  int px = idx >> 6;
  int b = px >> 12;
  int rem = px & 4095;
  int y = rem >> 6, xc = rem & 63;
  int ci = k >> 4, t = k & 15;
  int ky = t >> 2, kx = t & 3;
  float v = 0.f;
  if (ci < 3) {
    int iy = 2 * y - 1 + ky, ix = 2 * xc - 1 + kx;
    if ((unsigned)iy < 128u && (unsigned)ix < 128u)
      v = x[((b * 3 + ci) * 128 + iy) * 128 + ix];
  }
  out[idx] = f2bf(v);
}

// deconv weights: w[ci][o][kk(16)] -> bf16 wdt[kk][o][ci]
__global__ __launch_bounds__(256) void k_wswz_dd(
    const float* __restrict__ w, short* __restrict__ wdt)
{
  int idx = blockIdx.x * 256 + threadIdx.x;
  if (idx >= 12288) return;
  int ci = idx & 255, t = idx >> 8;
  int o = t % 3, kk = t / 3;
  wdt[idx] = f2bf(w[(ci * 3 + o) * 16 + kk]);
}

// codebook norms |c|^2
__global__ __launch_bounds__(256) void k_ccn(
    const float* __restrict__ cb, float* __restrict__ cc)
{
  int code = blockIdx.x * 256 + threadIdx.x;
  const float4* r = (const float4*)(cb + (size_t)code * 256);
  float s = 0.f;
  for (int i = 0; i < 64; ++i) {
    float4 v = r[i];
    s += v.x * v.x + v.y * v.y + v.z * v.z + v.w * v.w;
  }
  cc[code] = s;
}

// ---------------- BN (batch stats) on NHWC bf16 ----------------
// grid 256 blocks x 128 pixels; lane covers 8 consecutive channels.
__global__ __launch_bounds__(256) void k_bnstat(
    const short* __restrict__ t, float* __restrict__ sums, int C)
{
  int tid = threadIdx.x, lane = tid & 63, sub = tid >> 6;
  int c0 = lane * 8;
  bool active = c0 < C;
  float s[8], s2[8];
  #pragma unroll
  for (int i = 0; i < 8; ++i) { s[i] = 0.f; s2[i] = 0.f; }
  int base_pix = blockIdx.x * 128;
  if (active) {
    for (int p = sub; p < 128; p += 4) {
      short8 v = *(const short8*)&t[(size_t)(base_pix + p) * C + c0];
      #pragma unroll
      for (int i = 0; i < 8; ++i) { float f = bf2f(v[i]); s[i] += f; s2[i] += f * f; }
    }
    #pragma unroll
    for (int i = 0; i < 8; ++i) {
      atomicAdd(&sums[c0 + i], s[i]);
      atomicAdd(&sums[C + c0 + i], s2[i]);
    }
  }
}

__global__ __launch_bounds__(512) void k_bnfin(
    const float* __restrict__ sums, const float* __restrict__ g,
    const float* __restrict__ beta, float* __restrict__ ss, int C)
{
  int c = threadIdx.x;
  if (c >= C) return;
  float m = sums[c] * (1.f / 32768.f);
  float var = sums[C + c] * (1.f / 32768.f) - m * m;
  float sc = g[c] * rsqrtf(var + 1e-5f);
  ss[c] = sc;
  ss[C + c] = beta[c] - m * sc;
}

// thread handles 8 consecutive shorts
__global__ __launch_bounds__(256) void k_bnapply(
    short* __restrict__ t, const float* __restrict__ ss, int C)
{
  size_t base = ((size_t)blockIdx.x * 256 + threadIdx.x) * 8;
  int c = (int)(base & (size_t)(C - 1));
  short8 v = *(const short8*)&t[base];
  floatx4 sc0 = *(const floatx4*)&ss[c];
  floatx4 sc1 = *(const floatx4*)&ss[c + 4];
  floatx4 sh0 = *(const floatx4*)&ss[C + c];
  floatx4 sh1 = *(const floatx4*)&ss[C + c + 4];
  short8 o;
  #pragma unroll
  for (int i = 0; i < 4; ++i) {
    float a = bf2f(v[i]) * sc0[i] + sh0[i];
    float b = bf2f(v[4 + i]) * sc1[i] + sh1[i];
    o[i] = f2bf(a > 0.f ? a : 0.f);
    o[4 + i] = f2bf(b > 0.f ? b : 0.f);
  }
  *(short8*)&t[base] = o;
}

// ---------------- MFMA implicit-GEMM conv, NHWC bf16 ----------------
// Block: 256 thr = 4 waves = (2 rows) x (2 co-halves); wave tile 64co x 64px.
// Grid: (Cout/128 or K-split, 32 y-pairs, 8 b).
template <int K>
__global__ __launch_bounds__(256) void k_mconv(
    const short* __restrict__ in, short* __restrict__ out,
    short* __restrict__ outf,
    const short* __restrict__ sA, const short* __restrict__ sB,
    const float* __restrict__ bias_t,
    const short* __restrict__ wq, const float* __restrict__ bias,
    int Cin, int c0, int c1, int Cout, int flags)
{
  constexpr int K2 = K * K;
  constexpr int XS = 40;                 // padded x stride (ushorts)
  constexpr int NR = (K == 3) ? 4 : 1;
  constexpr int NX = (K == 3) ? 66 : 128;
  __shared__ __align__(16) short s_in[NR * NX * XS];
  __shared__ float btl[128];

  int tid = threadIdx.x;
  int lane = tid & 63;
  int wave = tid >> 6;
  int m = lane & 15, quad = lane >> 4;
  int wr = wave >> 1, wc = wave & 1;
  int y2 = blockIdx.y * 2, b = blockIdx.z;
  int coblk = (flags & F_SPLIT) ? 0 : blockIdx.x;
  int nch = Cin >> 5;

  if ((flags & F_IN_BFPAIR) && tid < 128) btl[tid] = bias_t[tid];

  int cc0 = c0, cc1 = c1;
  if (flags & F_SPLIT) {
    int half = nch >> 1;
    cc0 = blockIdx.x * half; cc1 = cc0 + half;
    outf += (size_t)blockIdx.x * 4194304;
  }

  floatx4 acc[4][4];
  #pragma unroll
  for (int f = 0; f < 4; ++f)
    #pragma unroll
    for (int p = 0; p < 4; ++p) acc[f][p] = (floatx4){0.f, 0.f, 0.f, 0.f};

  for (int cich = cc0; cich < cc1; ++cich) {
    __syncthreads();
    if (K == 3) {
      for (int u = tid; u < 4 * 66 * 4; u += 256) {
        int o = u & 3; int t2 = u >> 2;
        int xp = t2 % 66; int row = t2 / 66;
        int gy = y2 - 1 + row, gx = xp - 1;
        short8 v = {0, 0, 0, 0, 0, 0, 0, 0};
        if ((unsigned)gy < 64u && (unsigned)gx < 64u)
          v = *(const short8*)&in[((size_t)((b * 64 + gy) * 64 + gx)) * Cin + (cich << 5) + (o << 3)];
        if (flags & F_IN_RELU) {
          #pragma unroll
          for (int i = 0; i < 8; ++i) if (v[i] < 0) v[i] = 0;
        }
        *(short8*)&s_in[(row * 66 + xp) * XS + (o << 3)] = v;
      }
    } else {
      if (flags & F_IN_BFPAIR) {
        for (int u = tid; u < 512; u += 256) {
          int o = u & 3; int xp = u >> 2;
          int ch = (cich << 5) + (o << 3);
          size_t base = ((size_t)((b * 64 + y2) * 64 + xp)) * 128 + ch;
          short8 a0 = *(const short8*)&sA[base];
          short8 a1 = *(const short8*)&sB[base];
          short8 v;
          #pragma unroll
          for (int i = 0; i < 8; ++i) {
            float va = bf2f(a0[i]) + bf2f(a1[i]) + btl[ch + i];
            v[i] = f2bf(va > 0.f ? va : 0.f);
          }
          *(short8*)&s_in[xp * XS + (o << 3)] = v;
        }
      } else {
        for (int u = tid; u < 512; u += 256) {
          int o = u & 3; int xp = u >> 2;
          short8 v = *(const short8*)&in[((size_t)((b * 64 + y2) * 64 + xp)) * Cin + (cich << 5) + (o << 3)];
          if (flags & F_IN_RELU) {
            #pragma unroll
            for (int i = 0; i < 8; ++i) if (v[i] < 0) v[i] = 0;
          }
          *(short8*)&s_in[xp * XS + (o << 3)] = v;
        }
      }
    }
    __syncthreads();

    #pragma unroll
    for (int kk = 0; kk < K2; ++kk) {
      int ky = (K == 3) ? (kk / 3) : 0;
      int kx = (K == 3) ? (kk - ky * 3) : 0;
      short8 af[4];
      #pragma unroll
      for (int f = 0; f < 4; ++f) {
        int cg = coblk * 8 + wc * 4 + f;
        af[f] = *(const short8*)&wq[(((size_t)(cg * K2 + kk) * nch + cich) * 64 + lane) * 8];
      }
      #pragma unroll
      for (int p = 0; p < 4; ++p) {
        short8 bv;
        if (K == 3)
          bv = *(const short8*)&s_in[((wr + ky) * 66 + p * 16 + m + kx) * XS + (quad << 3)];
        else
          bv = *(const short8*)&s_in[(wr * 64 + p * 16 + m) * XS + (quad << 3)];
        #pragma unroll
        for (int f = 0; f < 4; ++f)
          acc[f][p] = __builtin_amdgcn_mfma_f32_16x16x32_bf16(af[f], bv, acc[f][p], 0, 0, 0);
      }
    }
  }

  int pixrow = (b * 64 + y2 + wr) * 64;

  if (flags & F_SPLIT) {
    #pragma unroll
    for (int f = 0; f < 4; ++f) {
      int co_l = wc * 64 + f * 16 + quad * 4;
      #pragma unroll
      for (int p = 0; p < 4; ++p) {
        int x = p * 16 + m;
        short4v sv;
        #pragma unroll
        for (int r = 0; r < 4; ++r) sv[r] = f2bf(acc[f][p][r]);
        *(short4v*)&outf[(size_t)(pixrow + x) * 128 + co_l] = sv;
      }
    }
    return;
  }

  #pragma unroll
  for (int f = 0; f < 4; ++f) {
    int co4 = coblk * 128 + wc * 64 + f * 16 + quad * 4;
    floatx4 bv4 = *(const floatx4*)&bias[co4];
    #pragma unroll
    for (int p = 0; p < 4; ++p) {
      int x = p * 16 + m;
      size_t oidx = (size_t)(pixrow + x) * Cout + co4;
      float v[4];
      #pragma unroll
      for (int r = 0; r < 4; ++r) v[r] = acc[f][p][r] + bv4[r];
      if (flags & F_RESIDUAL) {
        short4v rr = *(const short4v*)&out[oidx];
        #pragma unroll
        for (int r = 0; r < 4; ++r) v[r] += bf2f(rr[r]);
      }
      if (flags & F_OUT_RELU) {
        #pragma unroll
        for (int r = 0; r < 4; ++r) v[r] = v[r] > 0.f ? v[r] : 0.f;
      }
      short4v sv;
      #pragma unroll
      for (int r = 0; r < 4; ++r) sv[r] = f2bf(v[r]);
      *(short4v*)&out[oidx] = sv;
    }
  }
}

// ---------------- MFMA vector quantizer ----------------
__global__ __launch_bounds__(128) void k_vqm(
    const short* __restrict__ z, const short* __restrict__ cbq,
    const float* __restrict__ cb, const float* __restrict__ cc,
    short* __restrict__ zq, float* __restrict__ vq_sum)
{
  __shared__ __align__(16) short zl[64 * 264];
  __shared__ float ccl[1024];
  __shared__ int widx[64];
  __shared__ float red[128];

  int tid = threadIdx.x;
  int lane = tid & 63, wave = tid >> 6;
  int m = lane & 15, quad = lane >> 4;
  size_t px0 = (size_t)blockIdx.x * 64;

  for (int u = tid; u < 64 * 32; u += 128) {
    int px = u >> 5, o = u & 31;
    *(short8*)&zl[px * 264 + o * 8] = *(const short8*)&z[(px0 + px) * 256 + o * 8];
  }
  for (int u = tid; u < 1024; u += 128) ccl[u] = cc[u];
  __syncthreads();

  short8 bf[2][8];
  #pragma unroll
  for (int f = 0; f < 2; ++f) {
    int px = wave * 32 + f * 16 + m;
    #pragma unroll
    for (int kc = 0; kc < 8; ++kc)
      bf[f][kc] = *(const short8*)&zl[px * 264 + kc * 32 + quad * 8];
  }

  float best[2] = {3.4e38f, 3.4e38f};
  int bid[2] = {0, 0};

  for (int cg = 0; cg < 64; ++cg) {
    floatx4 acc0 = (floatx4){0.f, 0.f, 0.f, 0.f};
    floatx4 acc1 = (floatx4){0.f, 0.f, 0.f, 0.f};
    #pragma unroll
    for (int kc = 0; kc < 8; ++kc) {
      short8 af = *(const short8*)&cbq[((size_t)(cg * 8 + kc) * 64 + lane) * 8];
      acc0 = __builtin_amdgcn_mfma_f32_16x16x32_bf16(af, bf[0][kc], acc0, 0, 0, 0);
      acc1 = __builtin_amdgcn_mfma_f32_16x16x32_bf16(af, bf[1][kc], acc1, 0, 0, 0);
    }
    floatx4 c4 = *(const floatx4*)&ccl[cg * 16 + quad * 4];
    #pragma unroll
    for (int r = 0; r < 4; ++r) {
      int code = cg * 16 + quad * 4 + r;
      float s0 = c4[r] - 2.f * acc0[r];
      float s1 = c4[r] - 2.f * acc1[r];
      if (s0 < best[0]) { best[0] = s0; bid[0] = code; }
      if (s1 < best[1]) { best[1] = s1; bid[1] = code; }
    }
  }

  #pragma unroll
  for (int f = 0; f < 2; ++f) {
    float s = best[f]; int i = bid[f];
    #pragma unroll
    for (int off = 16; off <= 32; off <<= 1) {
      float s2 = __shfl_xor(s, off);
      int i2 = __shfl_xor(i, off);
      if (s2 < s || (s2 == s && i2 < i)) { s = s2; i = i2; }
    }
    if (quad == 0) widx[wave * 32 + f * 16 + m] = i;
  }
  __syncthreads();

  float local = 0.f;
  for (int px = 0; px < 64; ++px) {
    int code = widx[px];
    #pragma unroll
    for (int k = 0; k < 2; ++k) {
      int d = tid + k * 128;
      float q = cb[(size_t)code * 256 + d];
      float zv = bf2f(zl[px * 264 + d]);
      float df = q - zv;
      local += df * df;
      zq[(px0 + px) * 256 + d] = f2bf(q);
    }
  }
  red[tid] = local;
  __syncthreads();
  for (int off = 64; off > 0; off >>= 1) {
    if (tid < off) red[tid] += red[tid + off];
    __syncthreads();
  }
  if (tid == 0) atomicAdd(vq_sum, red[0]);
}

// ---------------- deconv 256->3, k4 s2 p1 (NHWC bf16 in, NCHW fp32 out) ----
__global__ __launch_bounds__(256) void k_deconv(
    const short* __restrict__ h, const short* __restrict__ wdt,
    const float* __restrict__ bias, const float* __restrict__ x,
    float* __restrict__ xr, float* __restrict__ recon_sum)
{
  __shared__ float red[256];
  int idx = blockIdx.x * 256 + threadIdx.x;
  int xc = idx & 127;
  int yc = (idx >> 7) & 127;
  int b = idx >> 14;

  int vy[2], vky[2], nvy = 0;
  int ky0 = (yc + 1) & 1;
  #pragma unroll
  for (int t = 0; t < 2; ++t) {
    int ky = ky0 + 2 * t;
    int iy = (yc + 1 - ky) >> 1;
    if (iy >= 0 && iy < 64) { vky[nvy] = ky; vy[nvy] = iy; ++nvy; }
  }
  int vx[2], vkx[2], nvx = 0;
  int kx0 = (xc + 1) & 1;
  #pragma unroll
  for (int t = 0; t < 2; ++t) {
    int kx = kx0 + 2 * t;
    int ix = (xc + 1 - kx) >> 1;
    if (ix >= 0 && ix < 64) { vkx[nvx] = kx; vx[nvx] = ix; ++nvx; }
  }

  float acc[3] = {bias[0], bias[1], bias[2]};
  for (int ty = 0; ty < nvy; ++ty)
    for (int tx = 0; tx < nvx; ++tx) {
      int kk = vky[ty] * 4 + vkx[tx];
      const short* hp = h + ((size_t)((b * 64 + vy[ty]) * 64 + vx[tx])) * 256;
      const short* wp = wdt + kk * 768;
      for (int c = 0; c < 256; c += 8) {
        short8 hv = *(const short8*)&hp[c];
        short8 w0 = *(const short8*)&wp[c];
        short8 w1 = *(const short8*)&wp[256 + c];
        short8 w2 = *(const short8*)&wp[512 + c];
        #pragma unroll
        for (int i = 0; i < 8; ++i) {
          float hf = bf2f(hv[i]);
          acc[0] += hf * bf2f(w0[i]);
          acc[1] += hf * bf2f(w1[i]);
          acc[2] += hf * bf2f(w2[i]);
        }
      }
    }

  float local = 0.f;
  #pragma unroll
  for (int o = 0; o < 3; ++o) {
    size_t oi = ((size_t)(b * 3 + o) * 128 + yc) * 128 + xc;
    xr[oi] = acc[o];
    float df = acc[o] - x[oi];
    local += df * df;
  }
  red[threadIdx.x] = local;
  __syncthreads();
  for (int off = 128; off > 0; off >>= 1) {
    if (threadIdx.x < off) red[threadIdx.x] += red[threadIdx.x + off];
    __syncthreads();
  }
  if (threadIdx.x == 0) atomicAdd(recon_sum, red[0]);
}

// ---------------- finalize ----------------
__global__ void k_finalize(const float* __restrict__ a, float* __restrict__ out)
{
  float e = a[0] * (1.f / (32768.f * 256.f));
  float recon = a[1] * (1.f / 393216.f);
  out[393216] = recon + 1.25f * e;
  out[393217] = recon;
}

// ---------------------------------------------------------------------------
extern "C" void kernel_launch(void* const* d_in, const int* in_sizes, int n_in,
                              void* d_out, int out_size, void* d_ws, size_t ws_size,
                              hipStream_t stream)
{
  const float* x    = (const float*)d_in[0];
  const float* ec0w = (const float*)d_in[1];
  const float* ec0b = (const float*)d_in[2];
  const float* bn0g = (const float*)d_in[3];
  const float* bn0b = (const float*)d_in[4];
  const float* ec1w = (const float*)d_in[5];
  const float* ec1b = (const float*)d_in[6];
  const float* bn1g = (const float*)d_in[7];
  const float* bn1b = (const float*)d_in[8];
  const float* ec2w = (const float*)d_in[9];
  const float* ec2b = (const float*)d_in[10];
  const float* erw1 = (const float*)d_in[11];
  const float* erb1 = (const float*)d_in[12];
  const float* erw2 = (const float*)d_in[13];
  const float* erb2 = (const float*)d_in[14];
  const float* ec3w = (const float*)d_in[15];
  const float* ec3b = (const float*)d_in[16];
  const float* cb   = (const float*)d_in[17];
  const float* dc0w = (const float*)d_in[18];
  const float* dc0b = (const float*)d_in[19];
  const float* drw1 = (const float*)d_in[20];
  const float* drb1 = (const float*)d_in[21];
  const float* drw2 = (const float*)d_in[22];
  const float* drb2 = (const float*)d_in[23];
  const float* dc1w = (const float*)d_in[24];
  const float* dc1b = (const float*)d_in[25];
  const float* ddw  = (const float*)d_in[26];
  const float* ddb  = (const float*)d_in[27];

  short* wsu = (short*)d_ws;
  short* wq_ec1 = wsu;                       // 1,179,648
  short* wq_ec2 = wsu + 1179648;             // 2,359,296
  short* wq_ec3 = wsu + 3538944;             // 1,179,648
  short* wq_dc0 = wsu + 4718592;             // 1,179,648
  short* wq_dc1 = wsu + 5898240;             // 1,179,648
  short* wq_er1 = wsu + 7077888;             // 16 x 589,824
  short* wq_er2 = wsu + 16515072;            // 16 x 65,536
  short* wq_dr1 = wsu + 17563648;            // 16 x 589,824
  short* wq_dr2 = wsu + 27000832;            // 16 x 65,536
  short* wq_dd  = wsu + 28049408;            // 12,288
  short* cbq    = wsu + 28061696;            // 262,144
  short* wq0    = wsu + 28323840;            // 16,384 (conv0 A-frags, K pad 64)
  short* im2c   = wsu + 28340224;            // 2,097,152 ([32768][64])
  short* bufA   = wsu + 30437376;            // 16,777,216 (NHWC, C<=512)
  short* bufB   = wsu + 47214592;            // 16,777,216
  short* bufZ   = wsu + 63991808;            //  8,388,608 (C=256)
  short* scr    = wsu + 72380416;            //  8,388,608 (2 x bf16 split halves)
  float* stats  = (float*)(wsu + 80769024);
  float* bn0_sums = stats;         float* bn0_ss = stats + 512;
  float* bn1_sums = stats + 1024;  float* bn1_ss = stats + 2048;
  float* accums   = stats + 3072;
  float* ccn      = stats + 3080;            // 1024 codebook norms

  k_init<<<1, 256, 0, stream>>>(stats);

  // ---- weight swizzles ----
  k_wswz0m<<<64, 256, 0, stream>>>(ec0w, wq0);
  k_wswz_dd<<<48, 256, 0, stream>>>(ddw, wq_dd);
  k_ccn<<<4, 256, 0, stream>>>(cb, ccn);
  k_wswz<<<1024, 256, 0, stream>>>(cb, cbq, 256, 1, 262144);
  k_wswz<<<4608, 256, 0, stream>>>(ec1w, wq_ec1, 256, 9, 1179648);
  k_wswz<<<9216, 256, 0, stream>>>(ec2w, wq_ec2, 512, 9, 2359296);
  k_wswz<<<4608, 256, 0, stream>>>(ec3w, wq_ec3, 512, 9, 1179648);
  k_wswz<<<4608, 256, 0, stream>>>(dc0w, wq_dc0, 256, 9, 1179648);
  k_wswz<<<4608, 256, 0, stream>>>(dc1w, wq_dc1, 512, 9, 1179648);
  k_wswz<<<dim3(2304, 16), 256, 0, stream>>>(erw1, wq_er1, 512, 9, 589824);
  k_wswz<<<dim3(256, 16), 256, 0, stream>>>(erw2, wq_er2, 128, 1, 65536);
  k_wswz<<<dim3(2304, 16), 256, 0, stream>>>(drw1, wq_dr1, 512, 9, 589824);
  k_wswz<<<dim3(256, 16), 256, 0, stream>>>(drw2, wq_dr2, 128, 1, 65536);

  // ---- encoder ----
  k_im2col<<<8192, 256, 0, stream>>>(x, im2c);
  k_mconv<1><<<dim3(2, 32, 8), 256, 0, stream>>>(im2c, bufA, nullptr, nullptr, nullptr, nullptr,
                                                 wq0, ec0b, 64, 0, 2, 256, 0);
  k_bnstat<<<256, 256, 0, stream>>>(bufA, bn0_sums, 256);
  k_bnfin<<<1, 512, 0, stream>>>(bn0_sums, bn0g, bn0b, bn0_ss, 256);
  k_bnapply<<<4096, 256, 0, stream>>>(bufA, bn0_ss, 256);

  k_mconv<3><<<dim3(4, 32, 8), 256, 0, stream>>>(bufA, bufB, nullptr, nullptr, nullptr, nullptr,
                                                 wq_ec1, ec1b, 256, 0, 8, 512, 0);
  k_bnstat<<<256, 256, 0, stream>>>(bufB, bn1_sums, 512);
  k_bnfin<<<1, 512, 0, stream>>>(bn1_sums, bn1g, bn1b, bn1_ss, 512);
  k_bnapply<<<8192, 256, 0, stream>>>(bufB, bn1_ss, 512);

  k_mconv<3><<<dim3(4, 32, 8), 256, 0, stream>>>(bufB, bufA, nullptr, nullptr, nullptr, nullptr,
                                                 wq_ec2, ec2b, 512, 0, 16, 512, 0);

  for (int l = 0; l < 16; ++l) {
    k_mconv<3><<<dim3(2, 32, 8), 256, 0, stream>>>(bufA, nullptr, scr, nullptr, nullptr, nullptr,
                                                   wq_er1 + (size_t)l * 589824, nullptr,
                                                   512, 0, 0, 128, F_IN_RELU | F_SPLIT);
    k_mconv<1><<<dim3(4, 32, 8), 256, 0, stream>>>(nullptr, bufA, nullptr, scr, scr + 4194304,
                                                   erb1 + l * 128,
                                                   wq_er2 + (size_t)l * 65536, erb2 + l * 512,
                                                   128, 0, 4, 512,
                                                   F_IN_BFPAIR | F_RESIDUAL | (((l & 3) == 3) ? F_OUT_RELU : 0));
  }
  k_mconv<3><<<dim3(2, 32, 8), 256, 0, stream>>>(bufA, bufZ, nullptr, nullptr, nullptr, nullptr,
                                                 wq_ec3, ec3b, 512, 0, 16, 256, 0);

  // ---- VQ ----
  k_vqm<<<512, 128, 0, stream>>>(bufZ, cbq, cb, ccn, bufB, accums + 0);

  // ---- decoder ----
  k_mconv<3><<<dim3(4, 32, 8), 256, 0, stream>>>(bufB, bufA, nullptr, nullptr, nullptr, nullptr,
                                                 wq_dc0, dc0b, 256, 0, 8, 512, 0);
  for (int l = 0; l < 16; ++l) {
    k_mconv<3><<<dim3(2, 32, 8), 256, 0, stream>>>(bufA, nullptr, scr, nullptr, nullptr, nullptr,
                                                   wq_dr1 + (size_t)l * 589824, nullptr,
                                                   512, 0, 0, 128, F_IN_RELU | F_SPLIT);
    k_mconv<1><<<dim3(4, 32, 8), 256, 0, stream>>>(nullptr, bufA, nullptr, scr, scr + 4194304,
                                                   drb1 + l * 128,
                                                   wq_dr2 + (size_t)l * 65536, drb2 + l * 512,
                                                   128, 0, 4, 512,
                                                   F_IN_BFPAIR | F_RESIDUAL | (((l & 3) == 3) ? F_OUT_RELU : 0));
  }
  k_mconv<3><<<dim3(2, 32, 8), 256, 0, stream>>>(bufA, bufB, nullptr, nullptr, nullptr, nullptr,
                                                 wq_dc1, dc1b, 512, 0, 16, 256, F_OUT_RELU);

  // ---- deconv + losses ----
  k_deconv<<<512, 256, 0, stream>>>(bufB, wq_dd, ddb, x, (float*)d_out, accums + 1);
  k_finalize<<<1, 1, 0, stream>>>(accums, (float*)d_out);
}